// Round 6
// baseline (540.859 us; speedup 1.0000x reference)
//
#include <hip/hip_runtime.h>
#include <hip/hip_bf16.h>
#include <hip/hip_cooperative_groups.h>
#include <stdint.h>

namespace cg = cooperative_groups;

#define B_   8
#define S_   4096
#define SP1_ 4097
#define D_   256
#define R_   512
#define C_   2048

typedef __attribute__((ext_vector_type(8))) short bf16x8;
typedef __attribute__((ext_vector_type(4))) float f32x4;
typedef unsigned short u16;

__device__ __forceinline__ u16 f2bf(float f) {
  __hip_bfloat16 h = __float2bfloat16(f);
  return *(u16*)&h;
}
__device__ __forceinline__ float bf2f(u16 u) {
  __hip_bfloat16 h = *(__hip_bfloat16*)&u;
  return __bfloat162float(h);
}

// async global->LDS, 16B per lane; LDS dst = wave-uniform base + lane*16
__device__ __forceinline__ void gload16(const u16* g, u16* l) {
  __builtin_amdgcn_global_load_lds(
      (const __attribute__((address_space(1))) uint32_t*)g,
      (__attribute__((address_space(3))) uint32_t*)l, 16, 0, 0);
}

// ---------------- shared-memory union (max = dist phase = 141824 B, same as R3) ----------------
struct PrepSm { float w[512]; float bb[512]; float tile[2][1056]; };
struct EmbSm  { u16 tA[2][2][4096]; u16 tB[2][2][8192]; };        // [inst][dbuf][...]
struct DistSm { u16 b0[128 * 256]; u16 b1[128 * 256]; float esq[2048];
                float pbv[2][128]; int pbi[2][128]; int fidx[128]; };
union SMem { PrepSm prep; EmbSm emb; DistSm dist; };

// ============================ the megakernel ============================
// grid 256 x 512 thr (cooperative, 1 block/CU). Phases separated by grid sync:
//  A: zero | cast+qsq | E-transpose | (blk<8) cls copy + w0 + softmax
//  B: emb GEMM (2 tile-instances per block, waves 0-3 / 4-7)
//  C: dist (verbatim R3 72.5us kernel: 128-row tiles, areg[2][8], static dbuf)
//  D: block 0: perplexity + scalars
__global__ __launch_bounds__(512, 2) void k_mega(
    const float* __restrict__ x, const float* __restrict__ E,
    const float* __restrict__ clsw, const float* __restrict__ clsb,
    u16* __restrict__ posb, float* __restrict__ qsq,
    u16* __restrict__ ET, float* __restrict__ esq,
    int* __restrict__ hist, float* __restrict__ accbuf,
    u16* __restrict__ proj, u16* __restrict__ embT,
    float* __restrict__ out) {
  __shared__ SMem sm;
  __shared__ float smP[8];
  cg::grid_group grid = cg::this_grid();
  int blk = blockIdx.x, tid = threadIdx.x;
  int wv = tid >> 6, lane = tid & 63;

  // ---------------- PHASE A ----------------
  // zero esq+hist+acc (contiguous 32832 u32 starting at esq)
  { int o = blk * 512 + tid; if (o < 32832) ((uint32_t*)esq)[o] = 0u; }

  // cast + qsq: 128 rows per block
  #pragma unroll 4
  for (int j = 0; j < 16; j++) {
    int row = blk * 128 + wv * 16 + j;
    int b = row >> 12, s = row & 4095;
    const float4 v = *(const float4*)(x + (size_t)b * SP1_ * D_ + (size_t)(s + 1) * D_ + lane * 4);
    ushort4 u;
    u.x = f2bf(v.x); u.y = f2bf(v.y); u.z = f2bf(v.z); u.w = f2bf(v.w);
    *(ushort4*)(posb + (size_t)row * D_ + lane * 4) = u;
    float ss = v.x * v.x + v.y * v.y + v.z * v.z + v.w * v.w;
    #pragma unroll
    for (int off = 1; off < 64; off <<= 1) ss += __shfl_xor(ss, off);
    if (lane == 0) qsq[row] = ss;
  }

  // E transpose: 4 tiles per block (two concurrent halves x 2 loops)
  {
    int half = tid >> 8, tl = tid & 255, tx = tl & 31, ty = tl >> 5;
    for (int lp = 0; lp < 2; lp++) {
      int id = blk * 4 + lp * 2 + half;        // 0..1023
      int c0 = (id & 63) * 32, r0 = (id >> 6) * 32;
      float (*tile)[33] = (float(*)[33])sm.prep.tile[half];
      __syncthreads();                          // protect tile reuse across lp
      #pragma unroll
      for (int i = 0; i < 4; i++)
        tile[ty + i * 8][tx] = E[(size_t)(r0 + ty + i * 8) * C_ + c0 + tx];
      __syncthreads();
      #pragma unroll
      for (int i = 0; i < 4; i++)
        ET[(size_t)(c0 + ty + i * 8) * R_ + r0 + tx] = f2bf(tile[tx][ty + i * 8]);
    }
  }

  // blocks 0..7: cls copy + w0 + softmax -> proj (R5-verified math; w/bb disjoint from tile)
  if (blk < 8) {
    int b = blk;
    size_t xb = (size_t)b * SP1_ * D_;
    if (tid < 64) *(float4*)(out + xb + tid * 4) = *(const float4*)(x + xb + tid * 4);
    const float* cls = x + xb;
    float a = 0.f;
    for (int d = 0; d < D_; d++) a += cls[d] * clsw[d * R_ + tid];
    sm.prep.w[tid]  = a;
    sm.prep.bb[tid] = clsb[tid];
    __syncthreads();
    for (int jj = 0; jj < 32; jj++) {           // 8 waves x 32 = 256 d-rows
      int d = wv * 32 + jj;
      float c = cls[d];
      float l[8];
      #pragma unroll
      for (int k = 0; k < 8; k++) { int r = lane + k * 64; l[k] = c * sm.prep.w[r] + sm.prep.bb[r]; }
      float m = l[0];
      #pragma unroll
      for (int k = 1; k < 8; k++) m = fmaxf(m, l[k]);
      #pragma unroll
      for (int off = 1; off < 64; off <<= 1) m = fmaxf(m, __shfl_xor(m, off));
      float e[8], s = 0.f;
      #pragma unroll
      for (int k = 0; k < 8; k++) { e[k] = expf(l[k] - m); s += e[k]; }
      #pragma unroll
      for (int off = 1; off < 64; off <<= 1) s += __shfl_xor(s, off);
      float inv = 1.0f / s;
      size_t base = ((size_t)b * D_ + d) * R_;
      #pragma unroll
      for (int k = 0; k < 8; k++) proj[base + lane + k * 64] = f2bf(e[k] * inv);
    }
  }
  __threadfence();
  grid.sync();

  // ---------------- PHASE B: emb GEMM (2 instances per block) ----------------
  {
    int inst = wv >> 2, wvl = wv & 3;
    int id = blk * 2 + inst;                    // 0..511
    int nt = id & 15, mt = (id >> 4) & 3, b = id >> 6;
    int n0 = nt * 128, m0 = mt * 64;
    const u16* A  = proj + (size_t)b * D_ * R_;
    const u16* Bt = ET;
    u16 (*tA)[4096] = sm.emb.tA[inst];
    u16 (*tB)[8192] = sm.emb.tB[inst];
    int ln = lane & 15, qd = lane >> 4;
    int srow8 = lane >> 3, sc = lane & 7;
    int gc = sc ^ srow8;                        // fetch chunk so slot sc holds chunk sc^(row&7)
    f32x4 eacc[8];
    #pragma unroll
    for (int nf = 0; nf < 8; nf++) eacc[nf] = (f32x4){0.f, 0.f, 0.f, 0.f};

#define STAGE_EMB(bufi, kkk) do {                                                   \
    _Pragma("unroll")                                                               \
    for (int i_ = 0; i_ < 2; i_++) {                                                \
      int r0_ = wvl * 16 + i_ * 8;                                                  \
      gload16(A + (size_t)(m0 + r0_ + srow8) * R_ + (kkk) + gc * 8,                 \
              &tA[bufi][r0_ * 64]);                                                 \
    }                                                                               \
    _Pragma("unroll")                                                               \
    for (int i_ = 0; i_ < 4; i_++) {                                                \
      int r0_ = wvl * 32 + i_ * 8;                                                  \
      gload16(Bt + (size_t)(n0 + r0_ + srow8) * R_ + (kkk) + gc * 8,                \
              &tB[bufi][r0_ * 64]);                                                 \
    }                                                                               \
  } while (0)

    STAGE_EMB(0, 0);
    __syncthreads();
    int cur = 0;
    for (int kk = 0; kk < R_; kk += 64) {
      int nxt = kk + 64;
      if (nxt < R_) STAGE_EMB(cur ^ 1, nxt);
      #pragma unroll
      for (int kc = 0; kc < 2; kc++) {
        int slot = (kc * 4 + qd) ^ (ln & 7);
        bf16x8 af = *(bf16x8*)&tA[cur][(wvl * 16 + ln) * 64 + slot * 8];
        bf16x8 bfr[8];
        #pragma unroll
        for (int nf = 0; nf < 8; nf++) bfr[nf] = *(bf16x8*)&tB[cur][(nf * 16 + ln) * 64 + slot * 8];
        #pragma unroll
        for (int nf = 0; nf < 8; nf++)
          eacc[nf] = __builtin_amdgcn_mfma_f32_16x16x32_bf16(af, bfr[nf], eacc[nf], 0, 0, 0);
      }
      __syncthreads();
      cur ^= 1;
    }
#undef STAGE_EMB
    // epilogue: row d = m0+wvl*16+qd*4+reg, col c = n0+nf*16+ln
    #pragma unroll
    for (int nf = 0; nf < 8; nf++) {
      int c = n0 + nf * 16 + ln;
      int dbase = m0 + wvl * 16 + qd * 4;
      f32x4 v = eacc[nf];
      ushort4 u;
      u.x = f2bf(v[0]); u.y = f2bf(v[1]); u.z = f2bf(v[2]); u.w = f2bf(v[3]);
      *(ushort4*)&embT[((size_t)b * C_ + c) * D_ + dbase] = u;
      float ss = v[0]*v[0] + v[1]*v[1] + v[2]*v[2] + v[3]*v[3];
      ss += __shfl_xor(ss, 16);
      ss += __shfl_xor(ss, 32);
      if (qd == 0) atomicAdd(&esq[b * C_ + c], ss);
    }
  }
  __threadfence();
  grid.sync();

  // ---------------- PHASE C: dist (verbatim R3 structure) ----------------
  {
    int b = blk & 7, st = blk >> 3;             // blk%8 = XCD id -> batch-pinned panels
    int m0 = st * 128;
    const u16* A  = posb + (size_t)b * S_ * D_;
    const u16* Bt = embT + (size_t)b * C_ * D_;
    int ln = lane & 15, qd = lane >> 4;
    int wr = wv >> 1, wc = wv & 1;

    *(float4*)&sm.dist.esq[tid * 4] = *(const float4*)&esq[b * C_ + tid * 4];

    bf16x8 areg[2][8];
    #pragma unroll
    for (int mi = 0; mi < 2; mi++) {
      const u16* ar = A + (size_t)(m0 + wr * 32 + mi * 16 + ln) * D_ + qd * 8;
      #pragma unroll
      for (int tt = 0; tt < 8; tt++) areg[mi][tt] = *(const bf16x8*)(ar + tt * 32);
    }

    float rbv[2][4]; int rbc[2][4];
    #pragma unroll
    for (int mi = 0; mi < 2; mi++)
      #pragma unroll
      for (int r = 0; r < 4; r++) { rbv[mi][r] = 3.4e38f; rbc[mi][r] = 0; }

#define STAGE_D(TB, ct) do {                                                        \
    _Pragma("unroll")                                                               \
    for (int i_ = 0; i_ < 8; i_++) {                                                \
      int c0_ = wv * 16 + i_ * 2;                                                   \
      int cl_ = c0_ + (lane >> 5);                                                  \
      int gc_ = (lane & 31) ^ (cl_ & 7);                                            \
      gload16(Bt + (size_t)((ct) * 128 + cl_) * D_ + gc_ * 8, (TB) + c0_ * 256);    \
    }                                                                               \
  } while (0)

#define COMPUTE_D(TB, ct) do {                                                      \
    f32x4 cacc[2][4];                                                               \
    _Pragma("unroll")                                                               \
    for (int mi_ = 0; mi_ < 2; mi_++)                                               \
      _Pragma("unroll")                                                             \
      for (int cf_ = 0; cf_ < 4; cf_++) cacc[mi_][cf_] = (f32x4){0.f,0.f,0.f,0.f};  \
    _Pragma("unroll")                                                               \
    for (int kt_ = 0; kt_ < 8; kt_++) {                                             \
      bf16x8 bfr[4];                                                                \
      _Pragma("unroll")                                                             \
      for (int cf_ = 0; cf_ < 4; cf_++) {                                           \
        int col_ = wc * 64 + cf_ * 16 + ln;                                         \
        int slot_ = (kt_ * 4 + qd) ^ (ln & 7);                                      \
        bfr[cf_] = *(bf16x8*)&(TB)[col_ * 256 + slot_ * 8];                         \
      }                                                                             \
      _Pragma("unroll")                                                             \
      for (int mi_ = 0; mi_ < 2; mi_++)                                             \
        _Pragma("unroll")                                                           \
        for (int cf_ = 0; cf_ < 4; cf_++)                                           \
          cacc[mi_][cf_] = __builtin_amdgcn_mfma_f32_16x16x32_bf16(                 \
              areg[mi_][kt_], bfr[cf_], cacc[mi_][cf_], 0, 0, 0);                   \
    }                                                                               \
    _Pragma("unroll")                                                               \
    for (int mi_ = 0; mi_ < 2; mi_++)                                               \
      _Pragma("unroll")                                                             \
      for (int cf_ = 0; cf_ < 4; cf_++) {                                           \
        int c_ = (ct) * 128 + wc * 64 + cf_ * 16 + ln;                              \
        float e_ = sm.dist.esq[c_];                                                 \
        _Pragma("unroll")                                                           \
        for (int r_ = 0; r_ < 4; r_++) {                                            \
          float s_ = e_ - 2.0f * cacc[mi_][cf_][r_];                                \
          if (s_ < rbv[mi_][r_] || (s_ == rbv[mi_][r_] && c_ < rbc[mi_][r_])) {     \
            rbv[mi_][r_] = s_; rbc[mi_][r_] = c_;                                   \
          }                                                                         \
        }                                                                           \
      }                                                                             \
  } while (0)

    STAGE_D(sm.dist.b0, 0);
    __syncthreads();
    for (int ct = 0; ct < 16; ct += 2) {
      STAGE_D(sm.dist.b1, ct + 1);
      COMPUTE_D(sm.dist.b0, ct);
      __syncthreads();
      if (ct + 2 < 16) STAGE_D(sm.dist.b0, ct + 2);
      COMPUTE_D(sm.dist.b1, ct + 1);
      __syncthreads();
    }
#undef STAGE_D
#undef COMPUTE_D

    #pragma unroll
    for (int mi = 0; mi < 2; mi++)
      #pragma unroll
      for (int r = 0; r < 4; r++) {
        float bv = rbv[mi][r]; int bc = rbc[mi][r];
        #pragma unroll
        for (int off = 1; off < 16; off <<= 1) {
          float ov = __shfl_xor(bv, off);
          int   oc = __shfl_xor(bc, off);
          if (ov < bv || (ov == bv && oc < bc)) { bv = ov; bc = oc; }
        }
        if (ln == 0) {
          int rl = wr * 32 + mi * 16 + qd * 4 + r;  // 0..127
          sm.dist.pbv[wc][rl] = bv;
          sm.dist.pbi[wc][rl] = bc;
        }
      }
    __syncthreads();
    if (tid < 128) {
      float v0 = sm.dist.pbv[0][tid]; int i0 = sm.dist.pbi[0][tid];
      float v1 = sm.dist.pbv[1][tid]; int i1 = sm.dist.pbi[1][tid];
      if (v1 < v0 || (v1 == v0 && i1 < i0)) { v0 = v1; i0 = i1; }
      sm.dist.fidx[tid] = i0;
      atomicAdd(&hist[b * C_ + i0], 1);
      float sse = v0 + qsq[b * S_ + m0 + tid];
      #pragma unroll
      for (int off = 1; off < 64; off <<= 1) sse += __shfl_xor(sse, off);
      if (lane == 0) atomicAdd(&accbuf[0], sse);
    }
    __syncthreads();
    size_t xb = (size_t)b * SP1_ * D_;
    #pragma unroll
    for (int j = 0; j < 16; j++) {
      int r = wv * 16 + j;
      int ix = sm.dist.fidx[r];
      int s = m0 + r;
      ushort4 q4 = *(const ushort4*)(Bt + (size_t)ix * D_ + lane * 4);
      float4 q;
      q.x = bf2f(q4.x); q.y = bf2f(q4.y); q.z = bf2f(q4.z); q.w = bf2f(q4.w);
      *(float4*)(out + xb + (size_t)(s + 1) * D_ + lane * 4) = q;
    }
  }
  __threadfence();
  grid.sync();

  // ---------------- PHASE D: perplexity + scalars (block 0) ----------------
  if (blk == 0) {
    int tb = tid >> 6, l64 = tid & 63;          // 8 batches x 64 lanes
    float ps = 0.f;
    for (int c = l64; c < C_; c += 64) {
      int h = atomicAdd(&hist[tb * C_ + c], 0); // coherent cross-XCD read
      float p = (float)h * (1.0f / (float)S_);
      ps += p * logf(p + 1e-10f);
    }
    #pragma unroll
    for (int off = 1; off < 64; off <<= 1) ps += __shfl_xor(ps, off);
    if (l64 == 0) smP[tb] = expf(-ps);
    __syncthreads();
    if (tid == 0) {
      float P = 0.f;
      #pragma unroll
      for (int i = 0; i < 8; i++) P += smP[i];
      P *= (1.0f / 8.0f);
      float SSE = atomicAdd(&accbuf[0], 0.0f);
      float L = SSE * (1.0f / 8388608.0f);
      size_t base = (size_t)B_ * SP1_ * D_;
      out[base + 0] = P;
      out[base + 1] = L;
      out[base + 2] = L;
      out[base + 3] = L + 0.25f * L;
    }
  }
}

// ---------------- workspace layout (bytes); esq/hist/acc contiguous (zeroed in phase A) ----------------
#define OFF_ESQ   16384u
#define OFF_HIST  (OFF_ESQ + 65536u)
#define OFF_ACC   (OFF_HIST + 65536u)
#define OFF_PROJ  (OFF_ACC + 256u)
#define OFF_ET    (OFF_PROJ + 2097152u)
#define OFF_EMBT  (OFF_ET + 2097152u)
#define OFF_POSB  (OFF_EMBT + 8388608u)
#define OFF_QSQ   (OFF_POSB + 16777216u)

extern "C" void kernel_launch(void* const* d_in, const int* in_sizes, int n_in,
                              void* d_out, int out_size, void* d_ws, size_t ws_size,
                              hipStream_t stream) {
  (void)in_sizes; (void)n_in; (void)out_size; (void)ws_size;
  const float* x    = (const float*)d_in[0];
  const float* E    = (const float*)d_in[1];
  const float* clsw = (const float*)d_in[2];
  const float* clsb = (const float*)d_in[3];
  float* out = (float*)d_out;

  char* ws = (char*)d_ws;
  float* esq  = (float*)(ws + OFF_ESQ);
  int*   hist = (int*)  (ws + OFF_HIST);
  float* acc  = (float*)(ws + OFF_ACC);
  u16*   proj = (u16*)  (ws + OFF_PROJ);
  u16*   ET   = (u16*)  (ws + OFF_ET);
  u16*   embT = (u16*)  (ws + OFF_EMBT);
  u16*   posb = (u16*)  (ws + OFF_POSB);
  float* qsq  = (float*)(ws + OFF_QSQ);

  void* kargs[] = { (void*)&x, (void*)&E, (void*)&clsw, (void*)&clsb,
                    (void*)&posb, (void*)&qsq, (void*)&ET, (void*)&esq,
                    (void*)&hist, (void*)&acc, (void*)&proj, (void*)&embT,
                    (void*)&out };
  hipLaunchCooperativeKernel((const void*)k_mega, dim3(256), dim3(512),
                             kargs, 0, stream);
}

// Round 7
// 253.903 us; speedup vs baseline: 2.1302x; 2.1302x over previous
//
#include <hip/hip_runtime.h>
#include <hip/hip_bf16.h>
#include <stdint.h>

#define B_   8
#define S_   4096
#define SP1_ 4097
#define D_   256
#define R_   512
#define C_   2048

typedef __attribute__((ext_vector_type(8))) short bf16x8;
typedef __attribute__((ext_vector_type(4))) float f32x4;
typedef unsigned short u16;

__device__ __forceinline__ u16 f2bf(float f) {
  __hip_bfloat16 h = __float2bfloat16(f);
  return *(u16*)&h;
}
__device__ __forceinline__ float bf2f(u16 u) {
  __hip_bfloat16 h = *(__hip_bfloat16*)&u;
  return __bfloat162float(h);
}

// async global->LDS, 16B per lane; LDS dst = wave-uniform base + lane*16
__device__ __forceinline__ void gload16(const u16* g, u16* l) {
  __builtin_amdgcn_global_load_lds(
      (const __attribute__((address_space(1))) uint32_t*)g,
      (__attribute__((address_space(3))) uint32_t*)l, 16, 0, 0);
}

// ======== K1: prep (softmax-per-batch | cast+qsq | transpose_E | zero | cls copy) ========
// R5-verified (passed). Softmax blocks first so they dispatch early and hide
// under the 8192 cast blocks.
#define SMAXB 8
#define NCAST 8192
#define NCB   (SMAXB + NCAST)    // 8200
#define TEB2  (NCB + 1024)       // 9224
#define ZB2   (TEB2 + 33)        // 9257
#define K1GRID (ZB2 + 8)         // 9265

__global__ void k_prep(const float* __restrict__ x, const float* __restrict__ clsw,
                       const float* __restrict__ clsb, const float* __restrict__ E,
                       u16* __restrict__ posb, float* __restrict__ qsq,
                       u16* __restrict__ ET, float* __restrict__ zbase,
                       u16* __restrict__ proj, float* __restrict__ out) {
  __shared__ float sm[33 * 32];               // 1056 floats (softmax uses 1024)
  int blk = blockIdx.x, t = threadIdx.x;
  if (blk < SMAXB) {
    int b = blk;
    const float* cls = x + (size_t)b * SP1_ * D_;
    float* w  = sm;                           // w0[512]
    float* bb = sm + 512;                     // clsb[512]
    float a0 = 0.f, a1 = 0.f;
    for (int d = 0; d < D_; d++) {
      float cd = cls[d];
      a0 += cd * clsw[d * R_ + t];
      a1 += cd * clsw[d * R_ + t + 256];
    }
    w[t] = a0; w[t + 256] = a1;
    bb[t] = clsb[t]; bb[t + 256] = clsb[t + 256];
    __syncthreads();
    int wv = t >> 6, lane = t & 63;
    for (int j = 0; j < 64; j++) {            // each wave: 64 of the 256 d-rows
      int d = wv * 64 + j;
      float c = cls[d];
      float l[8];
      #pragma unroll
      for (int k = 0; k < 8; k++) { int r = lane + k * 64; l[k] = c * w[r] + bb[r]; }
      float m = l[0];
      #pragma unroll
      for (int k = 1; k < 8; k++) m = fmaxf(m, l[k]);
      #pragma unroll
      for (int off = 1; off < 64; off <<= 1) m = fmaxf(m, __shfl_xor(m, off));
      float e[8], s = 0.f;
      #pragma unroll
      for (int k = 0; k < 8; k++) { e[k] = expf(l[k] - m); s += e[k]; }
      #pragma unroll
      for (int off = 1; off < 64; off <<= 1) s += __shfl_xor(s, off);
      float inv = 1.0f / s;
      size_t base = ((size_t)b * D_ + d) * R_;
      #pragma unroll
      for (int k = 0; k < 8; k++) proj[base + lane + k * 64] = f2bf(e[k] * inv);
    }
  } else if (blk < NCB) {
    int wv = t >> 6, lane = t & 63;
    int row = (blk - SMAXB) * 4 + wv;
    int b = row >> 12, s = row & 4095;
    const float4 v = *(const float4*)(x + (size_t)b * SP1_ * D_ + (size_t)(s + 1) * D_ + lane * 4);
    ushort4 u;
    u.x = f2bf(v.x); u.y = f2bf(v.y); u.z = f2bf(v.z); u.w = f2bf(v.w);
    *(ushort4*)(posb + (size_t)row * D_ + lane * 4) = u;
    float ss = v.x * v.x + v.y * v.y + v.z * v.z + v.w * v.w;
    #pragma unroll
    for (int off = 1; off < 64; off <<= 1) ss += __shfl_xor(ss, off);
    if (lane == 0) qsq[row] = ss;
  } else if (blk < TEB2) {
    int id = blk - NCB;                       // 0..1023
    int c0 = (id & 63) * 32, r0 = (id >> 6) * 32;
    int tx = t & 31, ty = t >> 5;             // 32 x 8
    float (*tile)[33] = (float(*)[33])sm;
    #pragma unroll
    for (int i = 0; i < 4; i++)
      tile[ty + i * 8][tx] = E[(size_t)(r0 + ty + i * 8) * C_ + c0 + tx];
    __syncthreads();
    #pragma unroll
    for (int i = 0; i < 4; i++)
      ET[(size_t)(c0 + ty + i * 8) * R_ + r0 + tx] = f2bf(tile[tx][ty + i * 8]);
  } else if (blk < ZB2) {
    int id = blk - TEB2;                      // 0..32  (zero esq+hist+acc = 131328 B)
    int o1 = id * 1024 + t;       if (o1 < 32832) ((uint32_t*)zbase)[o1] = 0u;
    int o2 = id * 1024 + 256 + t; if (o2 < 32832) ((uint32_t*)zbase)[o2] = 0u;
    int o3 = id * 1024 + 512 + t; if (o3 < 32832) ((uint32_t*)zbase)[o3] = 0u;
    int o4 = id * 1024 + 768 + t; if (o4 < 32832) ((uint32_t*)zbase)[o4] = 0u;
  } else {
    int b = blk - ZB2;
    size_t xb = (size_t)b * SP1_ * D_;
    if (t < 64) *(float4*)(out + xb + t * 4) = *(const float4*)(x + xb + t * 4);
  }
}

// ================= K3: emb GEMM, 2-phase double-buffered prefetch (R1-proven) =================
__global__ __launch_bounds__(256) void k_gemm_emb(const u16* __restrict__ proj,
                                                  const u16* __restrict__ ET,
                                                  u16* __restrict__ embT,
                                                  float* __restrict__ esq) {
  int nt = blockIdx.x, mt = blockIdx.y, b = blockIdx.z;
  int n0 = nt * 128, m0 = mt * 64;
  const u16* A  = proj + (size_t)b * D_ * R_;   // d-rows x R
  const u16* Bt = ET;                           // c-rows x R
  __shared__ u16 tA[2][64 * 64], tB[2][128 * 64];   // 16 KB + 32 KB (dbuf)
  int tid = threadIdx.x;
  int wv = tid >> 6, lane = tid & 63, ln = lane & 15, qd = lane >> 4;
  int srow8 = lane >> 3, sc = lane & 7;
  int gc = sc ^ srow8;                          // fetch chunk so slot sc holds chunk sc^(row&7)
  f32x4 acc[8];
  #pragma unroll
  for (int nf = 0; nf < 8; nf++) acc[nf] = (f32x4){0.f, 0.f, 0.f, 0.f};

#define STAGE_EMB(bufi, kkk) do {                                                   \
    _Pragma("unroll")                                                               \
    for (int i_ = 0; i_ < 2; i_++) {                                                \
      int r0_ = wv * 16 + i_ * 8;                                                   \
      gload16(A + (size_t)(m0 + r0_ + srow8) * R_ + (kkk) + gc * 8,                 \
              &tA[bufi][r0_ * 64]);                                                 \
    }                                                                               \
    _Pragma("unroll")                                                               \
    for (int i_ = 0; i_ < 4; i_++) {                                                \
      int r0_ = wv * 32 + i_ * 8;                                                   \
      gload16(Bt + (size_t)(n0 + r0_ + srow8) * R_ + (kkk) + gc * 8,                \
              &tB[bufi][r0_ * 64]);                                                 \
    }                                                                               \
  } while (0)

  STAGE_EMB(0, 0);
  __syncthreads();
  int cur = 0;
  for (int kk = 0; kk < R_; kk += 64) {
    int nxt = kk + 64;
    if (nxt < R_) STAGE_EMB(cur ^ 1, nxt);
    #pragma unroll
    for (int kc = 0; kc < 2; kc++) {
      int slot = (kc * 4 + qd) ^ (ln & 7);
      bf16x8 af = *(bf16x8*)&tA[cur][(wv * 16 + ln) * 64 + slot * 8];
      bf16x8 bfr[8];
      #pragma unroll
      for (int nf = 0; nf < 8; nf++) bfr[nf] = *(bf16x8*)&tB[cur][(nf * 16 + ln) * 64 + slot * 8];
      #pragma unroll
      for (int nf = 0; nf < 8; nf++)
        acc[nf] = __builtin_amdgcn_mfma_f32_16x16x32_bf16(af, bfr[nf], acc[nf], 0, 0, 0);
    }
    __syncthreads();
    cur ^= 1;
  }
#undef STAGE_EMB
  // epilogue: row d = m0+wv*16+qd*4+reg, col c = n0+nf*16+ln
  #pragma unroll
  for (int nf = 0; nf < 8; nf++) {
    int c = n0 + nf * 16 + ln;
    int dbase = m0 + wv * 16 + qd * 4;
    f32x4 v = acc[nf];
    ushort4 u;
    u.x = f2bf(v[0]); u.y = f2bf(v[1]); u.z = f2bf(v[2]); u.w = f2bf(v[3]);
    *(ushort4*)&embT[((size_t)b * C_ + c) * D_ + dbase] = u;
    float ss = v[0]*v[0] + v[1]*v[1] + v[2]*v[2] + v[3]*v[3];
    ss += __shfl_xor(ss, 16);
    ss += __shfl_xor(ss, 32);
    if (qd == 0) atomicAdd(&esq[b * C_ + c], ss);
  }
}

// ======== K4: dist — R3-verbatim structure (72.5us, VGPR 120) + done-counter perp tail ========
// Grid (8 b, 32 st) = 256 blocks (1/CU). 512 thr = 8 waves.
// Wave (wr,wc)=(wv>>1, wv&1): rows wr*32 (2 strips of 16), cols wc*64 per ct-tile.
// A (32 rows x K=256) in registers (areg[2][8] = 64 VGPR). B tile (128 cols x 256) in LDS,
// static double-buffer tB0/tB1 (distinct symbols -> alias analysis keeps prefetch async).
// LDS[col][slot16B] = global chunk slot^(col&7); read slot=(kt*4+qd)^(ln&7) (conflict-free).
__global__ __launch_bounds__(512) void k_dist(const u16* __restrict__ posb,
                                              const u16* __restrict__ embT,
                                              const float* __restrict__ esq,
                                              const float* __restrict__ qsq,
                                              int* __restrict__ hist,
                                              float* __restrict__ acc,
                                              float* __restrict__ out) {
  int b = blockIdx.x, st = blockIdx.y;
  int m0 = st * 128;
  const u16* A  = posb + (size_t)b * S_ * D_;   // S x D
  const u16* Bt = embT + (size_t)b * C_ * D_;   // C x D
  __shared__ u16 tB0[128 * 256];                // 64 KB
  __shared__ u16 tB1[128 * 256];                // 64 KB
  __shared__ float sh_esq[2048];                // 8 KB
  __shared__ float pbv[2][128];
  __shared__ int   pbi[2][128];
  __shared__ int   fidx[128];
  __shared__ float smP[8];
  __shared__ int   lastflag;
  int tid = threadIdx.x;
  int wv = tid >> 6, lane = tid & 63, ln = lane & 15, qd = lane >> 4;
  int wr = wv >> 1, wc = wv & 1;

  // esq -> LDS (2048 floats)
  *(float4*)&sh_esq[tid * 4] = *(const float4*)&esq[b * C_ + tid * 4];

  // A fragments -> registers
  bf16x8 areg[2][8];
  #pragma unroll
  for (int mi = 0; mi < 2; mi++) {
    const u16* ar = A + (size_t)(m0 + wr * 32 + mi * 16 + ln) * D_ + qd * 8;
    #pragma unroll
    for (int t = 0; t < 8; t++) areg[mi][t] = *(const bf16x8*)(ar + t * 32);
  }

  float rbv[2][4]; int rbc[2][4];
  #pragma unroll
  for (int mi = 0; mi < 2; mi++)
    #pragma unroll
    for (int r = 0; r < 4; r++) { rbv[mi][r] = 3.4e38f; rbc[mi][r] = 0; }

  // wave wv stages cols wv*16..wv*16+15; each gload16 covers 2 cols x 32 chunks
#define STAGE_D(TB, ct) do {                                                        \
    _Pragma("unroll")                                                               \
    for (int i_ = 0; i_ < 8; i_++) {                                                \
      int c0_ = wv * 16 + i_ * 2;                                                   \
      int cl_ = c0_ + (lane >> 5);                                                  \
      int gc_ = (lane & 31) ^ (cl_ & 7);                                            \
      gload16(Bt + (size_t)((ct) * 128 + cl_) * D_ + gc_ * 8, TB + c0_ * 256);      \
    }                                                                               \
  } while (0)

#define COMPUTE_D(TB, ct) do {                                                      \
    f32x4 cacc[2][4];                                                               \
    _Pragma("unroll")                                                               \
    for (int mi_ = 0; mi_ < 2; mi_++)                                               \
      _Pragma("unroll")                                                             \
      for (int cf_ = 0; cf_ < 4; cf_++) cacc[mi_][cf_] = (f32x4){0.f,0.f,0.f,0.f};  \
    _Pragma("unroll")                                                               \
    for (int kt_ = 0; kt_ < 8; kt_++) {                                             \
      bf16x8 bfr[4];                                                                \
      _Pragma("unroll")                                                             \
      for (int cf_ = 0; cf_ < 4; cf_++) {                                           \
        int col_ = wc * 64 + cf_ * 16 + ln;                                         \
        int slot_ = (kt_ * 4 + qd) ^ (ln & 7);                                      \
        bfr[cf_] = *(bf16x8*)&TB[col_ * 256 + slot_ * 8];                           \
      }                                                                             \
      _Pragma("unroll")                                                             \
      for (int mi_ = 0; mi_ < 2; mi_++)                                             \
        _Pragma("unroll")                                                           \
        for (int cf_ = 0; cf_ < 4; cf_++)                                           \
          cacc[mi_][cf_] = __builtin_amdgcn_mfma_f32_16x16x32_bf16(                 \
              areg[mi_][kt_], bfr[cf_], cacc[mi_][cf_], 0, 0, 0);                   \
    }                                                                               \
    _Pragma("unroll")                                                               \
    for (int mi_ = 0; mi_ < 2; mi_++)                                               \
      _Pragma("unroll")                                                             \
      for (int cf_ = 0; cf_ < 4; cf_++) {                                           \
        int c_ = (ct) * 128 + wc * 64 + cf_ * 16 + ln;                              \
        float e_ = sh_esq[c_];                                                      \
        _Pragma("unroll")                                                           \
        for (int r_ = 0; r_ < 4; r_++) {                                            \
          float s_ = e_ - 2.0f * cacc[mi_][cf_][r_];                                \
          if (s_ < rbv[mi_][r_] || (s_ == rbv[mi_][r_] && c_ < rbc[mi_][r_])) {     \
            rbv[mi_][r_] = s_; rbc[mi_][r_] = c_;                                   \
          }                                                                         \
        }                                                                           \
      }                                                                             \
  } while (0)

  STAGE_D(tB0, 0);
  __syncthreads();
  for (int ct = 0; ct < 16; ct += 2) {
    STAGE_D(tB1, ct + 1);                       // async prefetch (distinct symbol)
    COMPUTE_D(tB0, ct);
    __syncthreads();
    if (ct + 2 < 16) STAGE_D(tB0, ct + 2);
    COMPUTE_D(tB1, ct + 1);
    __syncthreads();
  }
#undef STAGE_D
#undef COMPUTE_D

  // 16-lane reduce per (mi, reg); row = wr*32 + mi*16 + qd*4 + reg
  #pragma unroll
  for (int mi = 0; mi < 2; mi++)
    #pragma unroll
    for (int r = 0; r < 4; r++) {
      float bv = rbv[mi][r]; int bc = rbc[mi][r];
      #pragma unroll
      for (int off = 1; off < 16; off <<= 1) {
        float ov = __shfl_xor(bv, off);
        int   oc = __shfl_xor(bc, off);
        if (ov < bv || (ov == bv && oc < bc)) { bv = ov; bc = oc; }
      }
      if (ln == 0) {
        int rl = wr * 32 + mi * 16 + qd * 4 + r;
        pbv[wc][rl] = bv;
        pbi[wc][rl] = bc;
      }
    }
  __syncthreads();
  // combine col-halves, hist, SSE
  if (tid < 128) {
    float v0 = pbv[0][tid]; int i0 = pbi[0][tid];
    float v1 = pbv[1][tid]; int i1 = pbi[1][tid];
    if (v1 < v0 || (v1 == v0 && i1 < i0)) { v0 = v1; i0 = i1; }
    fidx[tid] = i0;
    atomicAdd(&hist[b * C_ + i0], 1);
    float sse = v0 + qsq[b * S_ + m0 + tid];
    #pragma unroll
    for (int off = 1; off < 64; off <<= 1) sse += __shfl_xor(sse, off);
    if (lane == 0) atomicAdd(&acc[0], sse);
  }
  __syncthreads();
  // gather + write out (wave wv owns rows wv*16..+15)
  size_t xb = (size_t)b * SP1_ * D_;
  #pragma unroll
  for (int j = 0; j < 16; j++) {
    int r = wv * 16 + j;
    int ix = fidx[r];
    int s = m0 + r;
    ushort4 q4 = *(const ushort4*)(Bt + (size_t)ix * D_ + lane * 4);
    float4 q;
    q.x = bf2f(q4.x); q.y = bf2f(q4.y); q.z = bf2f(q4.z); q.w = bf2f(q4.w);
    *(float4*)(out + xb + (size_t)(s + 1) * D_ + lane * 4) = q;
  }

  // ---- last-block perplexity + scalars (device-scope done counter; R5-proven pattern) ----
  if (tid == 0) {
    __threadfence();
    int old = atomicAdd((int*)acc + 2, 1);
    lastflag = (old == 256 - 1);
  }
  __syncthreads();
  if (lastflag) {
    int tb = tid >> 6, l64 = tid & 63;          // 8 batches x 64 lanes
    float ps = 0.f;
    for (int c = l64; c < C_; c += 64) {
      int h = atomicAdd(&hist[tb * C_ + c], 0); // coherent cross-XCD read
      float p = (float)h * (1.0f / (float)S_);
      ps += p * logf(p + 1e-10f);
    }
    #pragma unroll
    for (int off = 1; off < 64; off <<= 1) ps += __shfl_xor(ps, off);
    if (l64 == 0) smP[tb] = expf(-ps);
    __syncthreads();
    if (tid == 0) {
      float P = 0.f;
      #pragma unroll
      for (int i = 0; i < 8; i++) P += smP[i];
      P *= (1.0f / 8.0f);
      float SSE = atomicAdd(&acc[0], 0.0f);
      float L = SSE * (1.0f / 8388608.0f);
      size_t base = (size_t)B_ * SP1_ * D_;
      out[base + 0] = P;
      out[base + 1] = L;
      out[base + 2] = L;
      out[base + 3] = L + 0.25f * L;
    }
  }
}

// ---------------- workspace layout (bytes); esq/hist/acc contiguous (zeroed by K1) ----------------
#define OFF_ESQ   16384u
#define OFF_HIST  (OFF_ESQ + 65536u)
#define OFF_ACC   (OFF_HIST + 65536u)
#define OFF_PROJ  (OFF_ACC + 256u)
#define OFF_ET    (OFF_PROJ + 2097152u)
#define OFF_EMBT  (OFF_ET + 2097152u)
#define OFF_POSB  (OFF_EMBT + 8388608u)
#define OFF_QSQ   (OFF_POSB + 16777216u)

extern "C" void kernel_launch(void* const* d_in, const int* in_sizes, int n_in,
                              void* d_out, int out_size, void* d_ws, size_t ws_size,
                              hipStream_t stream) {
  (void)in_sizes; (void)n_in; (void)out_size; (void)ws_size;
  const float* x    = (const float*)d_in[0];
  const float* E    = (const float*)d_in[1];
  const float* clsw = (const float*)d_in[2];
  const float* clsb = (const float*)d_in[3];
  float* out = (float*)d_out;

  char* ws = (char*)d_ws;
  float* esq  = (float*)(ws + OFF_ESQ);
  int*   hist = (int*)  (ws + OFF_HIST);
  float* acc  = (float*)(ws + OFF_ACC);
  u16*   proj = (u16*)  (ws + OFF_PROJ);
  u16*   ET   = (u16*)  (ws + OFF_ET);
  u16*   embT = (u16*)  (ws + OFF_EMBT);
  u16*   posb = (u16*)  (ws + OFF_POSB);
  float* qsq  = (float*)(ws + OFF_QSQ);

  k_prep<<<K1GRID, 256, 0, stream>>>(x, clsw, clsb, E, posb, qsq, ET, esq, proj, out);
  k_gemm_emb<<<dim3(16, 4, B_), 256, 0, stream>>>(proj, ET, embT, esq);
  k_dist<<<dim3(8, 32), 512, 0, stream>>>(posb, embT, esq, qsq, hist, acc, out);
}

// Round 8
// 193.381 us; speedup vs baseline: 2.7969x; 1.3130x over previous
//
#include <hip/hip_runtime.h>
#include <hip/hip_bf16.h>
#include <stdint.h>

#define B_   8
#define S_   4096
#define SP1_ 4097
#define D_   256
#define R_   512
#define C_   2048

typedef __attribute__((ext_vector_type(8))) short bf16x8;
typedef __attribute__((ext_vector_type(4))) float f32x4;
typedef unsigned short u16;

__device__ __forceinline__ u16 f2bf(float f) {
  __hip_bfloat16 h = __float2bfloat16(f);
  return *(u16*)&h;
}
__device__ __forceinline__ float bf2f(u16 u) {
  __hip_bfloat16 h = *(__hip_bfloat16*)&u;
  return __bfloat162float(h);
}

// async global->LDS, 16B per lane; LDS dst = wave-uniform base + lane*16
__device__ __forceinline__ void gload16(const u16* g, u16* l) {
  __builtin_amdgcn_global_load_lds(
      (const __attribute__((address_space(1))) uint32_t*)g,
      (__attribute__((address_space(3))) uint32_t*)l, 16, 0, 0);
}

// ======== K1: prep0 (w0 | transpose_E | zero | cls copy) — cast moved to K3 ========
#define W0B2  64                 // ids 0..63: w0
#define TEB3  (W0B2 + 1024)      // ids 64..1087: E transpose
#define ZB3   (TEB3 + 33)        // ids 1088..1120: zero esq/hist/acc
#define K1GRID (ZB3 + 8)         // ids 1121..1128: cls copy  -> 1129 blocks

__global__ void k_prep0(const float* __restrict__ x, const float* __restrict__ clsw,
                        const float* __restrict__ E, float* __restrict__ w0,
                        u16* __restrict__ ET, float* __restrict__ zbase,
                        float* __restrict__ out) {
  __shared__ float sm[33 * 32];
  int blk = blockIdx.x, t = threadIdx.x;
  if (blk < W0B2) {
    int id = blk;                             // 0..63 = b*8 + rc
    int b = id >> 3, rc = id & 7;
    int r = rc * 64 + (t & 63);
    int dg = t >> 6;
    const float* cls = x + (size_t)b * SP1_ * D_;
    float a = 0.f;
    for (int d = dg * 64; d < dg * 64 + 64; d++) a += cls[d] * clsw[d * R_ + r];
    sm[t] = a;
    __syncthreads();
    if (t < 64) w0[b * R_ + r] = sm[t] + sm[t + 64] + sm[t + 128] + sm[t + 192];
  } else if (blk < TEB3) {
    int id = blk - W0B2;                      // 0..1023
    int c0 = (id & 63) * 32, r0 = (id >> 6) * 32;
    int tx = t & 31, ty = t >> 5;             // 32 x 8
    float (*tile)[33] = (float(*)[33])sm;
    #pragma unroll
    for (int i = 0; i < 4; i++)
      tile[ty + i * 8][tx] = E[(size_t)(r0 + ty + i * 8) * C_ + c0 + tx];
    __syncthreads();
    #pragma unroll
    for (int i = 0; i < 4; i++)
      ET[(size_t)(c0 + ty + i * 8) * R_ + r0 + tx] = f2bf(tile[tx][ty + i * 8]);
  } else if (blk < ZB3) {
    int id = blk - TEB3;                      // 0..32  (zero esq+hist+acc = 131328 B)
    int o1 = id * 1024 + t;       if (o1 < 32832) ((uint32_t*)zbase)[o1] = 0u;
    int o2 = id * 1024 + 256 + t; if (o2 < 32832) ((uint32_t*)zbase)[o2] = 0u;
    int o3 = id * 1024 + 512 + t; if (o3 < 32832) ((uint32_t*)zbase)[o3] = 0u;
    int o4 = id * 1024 + 768 + t; if (o4 < 32832) ((uint32_t*)zbase)[o4] = 0u;
  } else {
    int b = blk - ZB3;
    size_t xb = (size_t)b * SP1_ * D_;
    if (t < 64) *(float4*)(out + xb + t * 4) = *(const float4*)(x + xb + t * 4);
  }
}

// ================= K2: softmax -> proj bf16 (R0-proven, 2048 blocks) =================
__global__ void k_softmax(const float* __restrict__ x, const float* __restrict__ w0,
                          const float* __restrict__ clsb, u16* __restrict__ proj) {
  int bd = blockIdx.x;
  int b = bd >> 8, d = bd & 255;
  float c = x[(size_t)b * SP1_ * D_ + d];
  int t = threadIdx.x;
  float l0 = c * w0[b * R_ + t] + clsb[t];
  float l1 = c * w0[b * R_ + t + 256] + clsb[t + 256];
  __shared__ float red[256];
  red[t] = fmaxf(l0, l1);
  __syncthreads();
  for (int st = 128; st; st >>= 1) { if (t < st) red[t] = fmaxf(red[t], red[t + st]); __syncthreads(); }
  float m = red[0];
  __syncthreads();
  float e0 = expf(l0 - m), e1 = expf(l1 - m);
  red[t] = e0 + e1;
  __syncthreads();
  for (int st = 128; st; st >>= 1) { if (t < st) red[t] += red[t + st]; __syncthreads(); }
  float inv = 1.0f / red[0];
  size_t base = ((size_t)b * D_ + d) * R_;
  proj[base + t]       = f2bf(e0 * inv);
  proj[base + t + 256] = f2bf(e1 * inv);
}

// ======== K3: emb GEMM (ids 0..511, R1-proven body) + cast/qsq (ids 512..8703) ========
// emb blocks dispatch first (long poles); cast blocks co-reside and fill idle BW.
#define EMBN 512
#define CASTN 8192
__global__ __launch_bounds__(256) void k_embcast(const u16* __restrict__ proj,
                                                 const u16* __restrict__ ET,
                                                 const float* __restrict__ x,
                                                 u16* __restrict__ embT,
                                                 float* __restrict__ esq,
                                                 u16* __restrict__ posb,
                                                 float* __restrict__ qsq) {
  __shared__ u16 tA[2][64 * 64], tB[2][128 * 64];   // 16 KB + 32 KB (emb dbuf)
  int id = blockIdx.x, tid = threadIdx.x;
  int wv = tid >> 6, lane = tid & 63;
  if (id < EMBN) {
    // ---- emb GEMM tile: same linear decode as R3's dim3(16,4,8) grid ----
    int nt = id & 15, mt = (id >> 4) & 3, b = id >> 6;
    int n0 = nt * 128, m0 = mt * 64;
    const u16* A  = proj + (size_t)b * D_ * R_;   // d-rows x R
    const u16* Bt = ET;                           // c-rows x R
    int ln = lane & 15, qd = lane >> 4;
    int srow8 = lane >> 3, sc = lane & 7;
    int gc = sc ^ srow8;                          // fetch chunk so slot sc holds chunk sc^(row&7)
    f32x4 acc[8];
    #pragma unroll
    for (int nf = 0; nf < 8; nf++) acc[nf] = (f32x4){0.f, 0.f, 0.f, 0.f};

#define STAGE_EMB(bufi, kkk) do {                                                   \
    _Pragma("unroll")                                                               \
    for (int i_ = 0; i_ < 2; i_++) {                                                \
      int r0_ = wv * 16 + i_ * 8;                                                   \
      gload16(A + (size_t)(m0 + r0_ + srow8) * R_ + (kkk) + gc * 8,                 \
              &tA[bufi][r0_ * 64]);                                                 \
    }                                                                               \
    _Pragma("unroll")                                                               \
    for (int i_ = 0; i_ < 4; i_++) {                                                \
      int r0_ = wv * 32 + i_ * 8;                                                   \
      gload16(Bt + (size_t)(n0 + r0_ + srow8) * R_ + (kkk) + gc * 8,                \
              &tB[bufi][r0_ * 64]);                                                 \
    }                                                                               \
  } while (0)

    STAGE_EMB(0, 0);
    __syncthreads();
    int cur = 0;
    for (int kk = 0; kk < R_; kk += 64) {
      int nxt = kk + 64;
      if (nxt < R_) STAGE_EMB(cur ^ 1, nxt);
      #pragma unroll
      for (int kc = 0; kc < 2; kc++) {
        int slot = (kc * 4 + qd) ^ (ln & 7);
        bf16x8 af = *(bf16x8*)&tA[cur][(wv * 16 + ln) * 64 + slot * 8];
        bf16x8 bfr[8];
        #pragma unroll
        for (int nf = 0; nf < 8; nf++) bfr[nf] = *(bf16x8*)&tB[cur][(nf * 16 + ln) * 64 + slot * 8];
        #pragma unroll
        for (int nf = 0; nf < 8; nf++)
          acc[nf] = __builtin_amdgcn_mfma_f32_16x16x32_bf16(af, bfr[nf], acc[nf], 0, 0, 0);
      }
      __syncthreads();
      cur ^= 1;
    }
#undef STAGE_EMB
    // epilogue: row d = m0+wv*16+qd*4+reg, col c = n0+nf*16+ln
    #pragma unroll
    for (int nf = 0; nf < 8; nf++) {
      int c = n0 + nf * 16 + ln;
      int dbase = m0 + wv * 16 + qd * 4;
      f32x4 v = acc[nf];
      ushort4 u;
      u.x = f2bf(v[0]); u.y = f2bf(v[1]); u.z = f2bf(v[2]); u.w = f2bf(v[3]);
      *(ushort4*)&embT[((size_t)b * C_ + c) * D_ + dbase] = u;
      float ss = v[0]*v[0] + v[1]*v[1] + v[2]*v[2] + v[3]*v[3];
      ss += __shfl_xor(ss, 16);
      ss += __shfl_xor(ss, 32);
      if (qd == 0) atomicAdd(&esq[b * C_ + c], ss);
    }
  } else {
    // ---- cast + qsq: 4 rows per block (R0-proven body) ----
    int row = (id - EMBN) * 4 + wv;
    int b = row >> 12, s = row & 4095;
    const float4 v = *(const float4*)(x + (size_t)b * SP1_ * D_ + (size_t)(s + 1) * D_ + lane * 4);
    ushort4 u;
    u.x = f2bf(v.x); u.y = f2bf(v.y); u.z = f2bf(v.z); u.w = f2bf(v.w);
    *(ushort4*)(posb + (size_t)row * D_ + lane * 4) = u;
    float ss = v.x * v.x + v.y * v.y + v.z * v.z + v.w * v.w;
    #pragma unroll
    for (int off = 1; off < 64; off <<= 1) ss += __shfl_xor(ss, off);
    if (lane == 0) qsq[row] = ss;
  }
}

// ======== K4: dist — R3-VERBATIM (72.5us proven): persistent 128-row blocks, areg[2][8],
//          static-symbol dbuf, fused argmin+hist+SSE+gather. NO perp tail. ========
__global__ __launch_bounds__(512) void k_dist(const u16* __restrict__ posb,
                                              const u16* __restrict__ embT,
                                              const float* __restrict__ esq,
                                              const float* __restrict__ qsq,
                                              int* __restrict__ hist,
                                              float* __restrict__ acc,
                                              float* __restrict__ out) {
  int b = blockIdx.x, st = blockIdx.y;
  int m0 = st * 128;
  const u16* A  = posb + (size_t)b * S_ * D_;   // S x D
  const u16* Bt = embT + (size_t)b * C_ * D_;   // C x D
  __shared__ u16 tB0[128 * 256];                // 64 KB
  __shared__ u16 tB1[128 * 256];                // 64 KB
  __shared__ float sh_esq[2048];                // 8 KB
  __shared__ float pbv[2][128];
  __shared__ int   pbi[2][128];
  __shared__ int   fidx[128];
  int tid = threadIdx.x;
  int wv = tid >> 6, lane = tid & 63, ln = lane & 15, qd = lane >> 4;
  int wr = wv >> 1, wc = wv & 1;

  *(float4*)&sh_esq[tid * 4] = *(const float4*)&esq[b * C_ + tid * 4];

  bf16x8 areg[2][8];
  #pragma unroll
  for (int mi = 0; mi < 2; mi++) {
    const u16* ar = A + (size_t)(m0 + wr * 32 + mi * 16 + ln) * D_ + qd * 8;
    #pragma unroll
    for (int t = 0; t < 8; t++) areg[mi][t] = *(const bf16x8*)(ar + t * 32);
  }

  float rbv[2][4]; int rbc[2][4];
  #pragma unroll
  for (int mi = 0; mi < 2; mi++)
    #pragma unroll
    for (int r = 0; r < 4; r++) { rbv[mi][r] = 3.4e38f; rbc[mi][r] = 0; }

#define STAGE_D(TB, ct) do {                                                        \
    _Pragma("unroll")                                                               \
    for (int i_ = 0; i_ < 8; i_++) {                                                \
      int c0_ = wv * 16 + i_ * 2;                                                   \
      int cl_ = c0_ + (lane >> 5);                                                  \
      int gc_ = (lane & 31) ^ (cl_ & 7);                                            \
      gload16(Bt + (size_t)((ct) * 128 + cl_) * D_ + gc_ * 8, TB + c0_ * 256);      \
    }                                                                               \
  } while (0)

#define COMPUTE_D(TB, ct) do {                                                      \
    f32x4 cacc[2][4];                                                               \
    _Pragma("unroll")                                                               \
    for (int mi_ = 0; mi_ < 2; mi_++)                                               \
      _Pragma("unroll")                                                             \
      for (int cf_ = 0; cf_ < 4; cf_++) cacc[mi_][cf_] = (f32x4){0.f,0.f,0.f,0.f};  \
    _Pragma("unroll")                                                               \
    for (int kt_ = 0; kt_ < 8; kt_++) {                                             \
      bf16x8 bfr[4];                                                                \
      _Pragma("unroll")                                                             \
      for (int cf_ = 0; cf_ < 4; cf_++) {                                           \
        int col_ = wc * 64 + cf_ * 16 + ln;                                         \
        int slot_ = (kt_ * 4 + qd) ^ (ln & 7);                                      \
        bfr[cf_] = *(bf16x8*)&TB[col_ * 256 + slot_ * 8];                           \
      }                                                                             \
      _Pragma("unroll")                                                             \
      for (int mi_ = 0; mi_ < 2; mi_++)                                             \
        _Pragma("unroll")                                                           \
        for (int cf_ = 0; cf_ < 4; cf_++)                                           \
          cacc[mi_][cf_] = __builtin_amdgcn_mfma_f32_16x16x32_bf16(                 \
              areg[mi_][kt_], bfr[cf_], cacc[mi_][cf_], 0, 0, 0);                   \
    }                                                                               \
    _Pragma("unroll")                                                               \
    for (int mi_ = 0; mi_ < 2; mi_++)                                               \
      _Pragma("unroll")                                                             \
      for (int cf_ = 0; cf_ < 4; cf_++) {                                           \
        int c_ = (ct) * 128 + wc * 64 + cf_ * 16 + ln;                              \
        float e_ = sh_esq[c_];                                                      \
        _Pragma("unroll")                                                           \
        for (int r_ = 0; r_ < 4; r_++) {                                            \
          float s_ = e_ - 2.0f * cacc[mi_][cf_][r_];                                \
          if (s_ < rbv[mi_][r_] || (s_ == rbv[mi_][r_] && c_ < rbc[mi_][r_])) {     \
            rbv[mi_][r_] = s_; rbc[mi_][r_] = c_;                                   \
          }                                                                         \
        }                                                                           \
      }                                                                             \
  } while (0)

  STAGE_D(tB0, 0);
  __syncthreads();
  for (int ct = 0; ct < 16; ct += 2) {
    STAGE_D(tB1, ct + 1);
    COMPUTE_D(tB0, ct);
    __syncthreads();
    if (ct + 2 < 16) STAGE_D(tB0, ct + 2);
    COMPUTE_D(tB1, ct + 1);
    __syncthreads();
  }
#undef STAGE_D
#undef COMPUTE_D

  #pragma unroll
  for (int mi = 0; mi < 2; mi++)
    #pragma unroll
    for (int r = 0; r < 4; r++) {
      float bv = rbv[mi][r]; int bc = rbc[mi][r];
      #pragma unroll
      for (int off = 1; off < 16; off <<= 1) {
        float ov = __shfl_xor(bv, off);
        int   oc = __shfl_xor(bc, off);
        if (ov < bv || (ov == bv && oc < bc)) { bv = ov; bc = oc; }
      }
      if (ln == 0) {
        int rl = wr * 32 + mi * 16 + qd * 4 + r;
        pbv[wc][rl] = bv;
        pbi[wc][rl] = bc;
      }
    }
  __syncthreads();
  if (tid < 128) {
    float v0 = pbv[0][tid]; int i0 = pbi[0][tid];
    float v1 = pbv[1][tid]; int i1 = pbi[1][tid];
    if (v1 < v0 || (v1 == v0 && i1 < i0)) { v0 = v1; i0 = i1; }
    fidx[tid] = i0;
    atomicAdd(&hist[b * C_ + i0], 1);
    float sse = v0 + qsq[b * S_ + m0 + tid];
    #pragma unroll
    for (int off = 1; off < 64; off <<= 1) sse += __shfl_xor(sse, off);
    if (lane == 0) atomicAdd(&acc[0], sse);
  }
  __syncthreads();
  size_t xb = (size_t)b * SP1_ * D_;
  #pragma unroll
  for (int j = 0; j < 16; j++) {
    int r = wv * 16 + j;
    int ix = fidx[r];
    int s = m0 + r;
    ushort4 q4 = *(const ushort4*)(Bt + (size_t)ix * D_ + lane * 4);
    float4 q;
    q.x = bf2f(q4.x); q.y = bf2f(q4.y); q.z = bf2f(q4.z); q.w = bf2f(q4.w);
    *(float4*)(out + xb + (size_t)(s + 1) * D_ + lane * 4) = q;
  }
}

// ================= K5: perplexity + final scalars (separate launch: plain hist loads) =================
__global__ void k_perp(const int* __restrict__ hist, float* __restrict__ acc,
                       float* __restrict__ out) {
  int b = blockIdx.x, t = threadIdx.x;
  float ps = 0.f;
  for (int c = t; c < C_; c += 256) {
    float p = (float)hist[b * C_ + c] * (1.0f / (float)S_);
    ps += p * logf(p + 1e-10f);
  }
  __shared__ float red[256];
  red[t] = ps;
  __syncthreads();
  for (int st = 128; st; st >>= 1) { if (t < st) red[t] += red[t + st]; __syncthreads(); }
  if (t == 0) {
    atomicAdd(&acc[1], expf(-red[0]) * (1.0f / (float)B_));
    __threadfence();
    int done = atomicAdd((int*)acc + 2, 1);
    if (done == B_ - 1) {
      float P = atomicAdd(&acc[1], 0.0f);
      float SSE = atomicAdd(&acc[0], 0.0f);
      float L = SSE * (1.0f / 8388608.0f);
      size_t base = (size_t)B_ * SP1_ * D_;
      out[base + 0] = P;
      out[base + 1] = L;
      out[base + 2] = L;
      out[base + 3] = L + 0.25f * L;
    }
  }
}

// ---------------- workspace layout (bytes); esq/hist/acc contiguous (zeroed by K1) ----------------
#define OFF_W0    0u
#define OFF_ESQ   16384u
#define OFF_HIST  (OFF_ESQ + 65536u)
#define OFF_ACC   (OFF_HIST + 65536u)
#define OFF_PROJ  (OFF_ACC + 256u)
#define OFF_ET    (OFF_PROJ + 2097152u)
#define OFF_EMBT  (OFF_ET + 2097152u)
#define OFF_POSB  (OFF_EMBT + 8388608u)
#define OFF_QSQ   (OFF_POSB + 16777216u)

extern "C" void kernel_launch(void* const* d_in, const int* in_sizes, int n_in,
                              void* d_out, int out_size, void* d_ws, size_t ws_size,
                              hipStream_t stream) {
  (void)in_sizes; (void)n_in; (void)out_size; (void)ws_size;
  const float* x    = (const float*)d_in[0];
  const float* E    = (const float*)d_in[1];
  const float* clsw = (const float*)d_in[2];
  const float* clsb = (const float*)d_in[3];
  float* out = (float*)d_out;

  char* ws = (char*)d_ws;
  float* w0   = (float*)(ws + OFF_W0);
  float* esq  = (float*)(ws + OFF_ESQ);
  int*   hist = (int*)  (ws + OFF_HIST);
  float* acc  = (float*)(ws + OFF_ACC);
  u16*   proj = (u16*)  (ws + OFF_PROJ);
  u16*   ET   = (u16*)  (ws + OFF_ET);
  u16*   embT = (u16*)  (ws + OFF_EMBT);
  u16*   posb = (u16*)  (ws + OFF_POSB);
  float* qsq  = (float*)(ws + OFF_QSQ);

  k_prep0<<<K1GRID, 256, 0, stream>>>(x, clsw, E, w0, ET, esq, out);
  k_softmax<<<B_ * D_, 256, 0, stream>>>(x, w0, clsb, proj);
  k_embcast<<<EMBN + CASTN, 256, 0, stream>>>(proj, ET, x, embT, esq, posb, qsq);
  k_dist<<<dim3(8, 32), 512, 0, stream>>>(posb, embT, esq, qsq, hist, acc, out);
  k_perp<<<B_, 256, 0, stream>>>(hist, acc, out);
}

// Round 9
// 190.944 us; speedup vs baseline: 2.8326x; 1.0128x over previous
//
#include <hip/hip_runtime.h>
#include <hip/hip_bf16.h>
#include <stdint.h>

#define B_   8
#define S_   4096
#define SP1_ 4097
#define D_   256
#define R_   512
#define C_   2048

typedef __attribute__((ext_vector_type(8))) short bf16x8;
typedef __attribute__((ext_vector_type(4))) float f32x4;
typedef unsigned short u16;

__device__ __forceinline__ u16 f2bf(float f) {
  __hip_bfloat16 h = __float2bfloat16(f);
  return *(u16*)&h;
}
__device__ __forceinline__ float bf2f(u16 u) {
  __hip_bfloat16 h = *(__hip_bfloat16*)&u;
  return __bfloat162float(h);
}

// async global->LDS, 16B per lane; LDS dst = wave-uniform base + lane*16
__device__ __forceinline__ void gload16(const u16* g, u16* l) {
  __builtin_amdgcn_global_load_lds(
      (const __attribute__((address_space(1))) uint32_t*)g,
      (__attribute__((address_space(3))) uint32_t*)l, 16, 0, 0);
}

// ================= K1: prep (cast+qsq | w0 | transpose_E | zero | cls copy) — R3-verbatim =================
#define NCAST 8192
#define W0B   (NCAST)            // 64 blocks
#define TEB   (W0B + 64)         // 1024 blocks
#define ZB    (TEB + 1024)       // 33 blocks
#define CLSB  (ZB + 33)          // 8 blocks
#define K1GRID (CLSB + 8)

__global__ void k_prep(const float* __restrict__ x, const float* __restrict__ clsw,
                       const float* __restrict__ E, u16* __restrict__ posb,
                       float* __restrict__ qsq, float* __restrict__ w0,
                       u16* __restrict__ ET, float* __restrict__ zbase,
                       float* __restrict__ out) {
  __shared__ float sm[33 * 32];
  int blk = blockIdx.x, t = threadIdx.x;
  if (blk < NCAST) {
    int wv = t >> 6, lane = t & 63;
    int row = blk * 4 + wv;
    int b = row >> 12, s = row & 4095;
    const float4 v = *(const float4*)(x + (size_t)b * SP1_ * D_ + (size_t)(s + 1) * D_ + lane * 4);
    ushort4 u;
    u.x = f2bf(v.x); u.y = f2bf(v.y); u.z = f2bf(v.z); u.w = f2bf(v.w);
    *(ushort4*)(posb + (size_t)row * D_ + lane * 4) = u;
    float ss = v.x * v.x + v.y * v.y + v.z * v.z + v.w * v.w;
    #pragma unroll
    for (int off = 1; off < 64; off <<= 1) ss += __shfl_xor(ss, off);
    if (lane == 0) qsq[row] = ss;
  } else if (blk < TEB) {
    int id = blk - W0B;                       // 0..63 = b*8 + rc
    int b = id >> 3, rc = id & 7;
    int r = rc * 64 + (t & 63);
    int dg = t >> 6;
    const float* cls = x + (size_t)b * SP1_ * D_;
    float a = 0.f;
    for (int d = dg * 64; d < dg * 64 + 64; d++) a += cls[d] * clsw[d * R_ + r];
    sm[t] = a;
    __syncthreads();
    if (t < 64) w0[b * R_ + r] = sm[t] + sm[t + 64] + sm[t + 128] + sm[t + 192];
  } else if (blk < ZB) {
    int id = blk - TEB;                       // 0..1023
    int c0 = (id & 63) * 32, r0 = (id >> 6) * 32;
    int tx = t & 31, ty = t >> 5;             // 32 x 8
    float (*tile)[33] = (float(*)[33])sm;
    #pragma unroll
    for (int i = 0; i < 4; i++)
      tile[ty + i * 8][tx] = E[(size_t)(r0 + ty + i * 8) * C_ + c0 + tx];
    __syncthreads();
    #pragma unroll
    for (int i = 0; i < 4; i++)
      ET[(size_t)(c0 + ty + i * 8) * R_ + r0 + tx] = f2bf(tile[tx][ty + i * 8]);
  } else if (blk < CLSB) {
    int id = blk - ZB;
    int o1 = id * 1024 + t;       if (o1 < 32832) ((uint32_t*)zbase)[o1] = 0u;
    int o2 = id * 1024 + 256 + t; if (o2 < 32832) ((uint32_t*)zbase)[o2] = 0u;
    int o3 = id * 1024 + 512 + t; if (o3 < 32832) ((uint32_t*)zbase)[o3] = 0u;
    int o4 = id * 1024 + 768 + t; if (o4 < 32832) ((uint32_t*)zbase)[o4] = 0u;
  } else {
    int b = blk - CLSB;
    size_t xb = (size_t)b * SP1_ * D_;
    if (t < 64) *(float4*)(out + xb + t * 4) = *(const float4*)(x + xb + t * 4);
  }
}

// ================= K2: softmax -> proj bf16 (R0-proven) =================
__global__ void k_softmax(const float* __restrict__ x, const float* __restrict__ w0,
                          const float* __restrict__ clsb, u16* __restrict__ proj) {
  int bd = blockIdx.x;
  int b = bd >> 8, d = bd & 255;
  float c = x[(size_t)b * SP1_ * D_ + d];
  int t = threadIdx.x;
  float l0 = c * w0[b * R_ + t] + clsb[t];
  float l1 = c * w0[b * R_ + t + 256] + clsb[t + 256];
  __shared__ float red[256];
  red[t] = fmaxf(l0, l1);
  __syncthreads();
  for (int st = 128; st; st >>= 1) { if (t < st) red[t] = fmaxf(red[t], red[t + st]); __syncthreads(); }
  float m = red[0];
  __syncthreads();
  float e0 = expf(l0 - m), e1 = expf(l1 - m);
  red[t] = e0 + e1;
  __syncthreads();
  for (int st = 128; st; st >>= 1) { if (t < st) red[t] += red[t + st]; __syncthreads(); }
  float inv = 1.0f / red[0];
  size_t base = ((size_t)b * D_ + d) * R_;
  proj[base + t]       = f2bf(e0 * inv);
  proj[base + t + 256] = f2bf(e1 * inv);
}

// ======== K3: emb2 — dist-R3-style persistent GEMM: embT[c][d] = sum_k ET[c][k]*proj[d][k] ========
// Grid (8 b, 32 cg) = 256 blocks = 1/CU. 512 thr = 8 waves, wave (wr,wc)=(wv>>1, wv&1).
// A = 64 ET c-rows (g0..g0+63) in registers: areg[16] = 64 VGPR (lane ln holds row g0+wr*16+ln).
// B = proj, streamed in 4 ct-tiles of 64 d-cols x K=512 = 64 KB LDS, static dbuf tE0/tE1.
// LDS slot s of row d holds global chunk s^(d&7); read slot=(kt*4+qd)^(ln&7) -> conflict-free
// (same verified swizzle family as k_dist). K-chunk order kt=0..15 identical to the old emb
// kernel -> embT bitwise identical. esq: deterministic in-block reduction (no atomics).
__global__ __launch_bounds__(512) void k_emb2(const u16* __restrict__ proj,
                                              const u16* __restrict__ ET,
                                              u16* __restrict__ embT,
                                              float* __restrict__ esq) {
  int b = blockIdx.x, cg = blockIdx.y;
  int g0 = cg * 64;
  const u16* Bp = proj + (size_t)b * D_ * R_;  // d-rows x R (B operand)
  __shared__ u16 tE0[64 * 512];                // 64 KB
  __shared__ u16 tE1[64 * 512];                // 64 KB
  __shared__ float sesq[2][64];
  int tid = threadIdx.x;
  int wv = tid >> 6, lane = tid & 63, ln = lane & 15, qd = lane >> 4;
  int wr = wv >> 1, wc = wv & 1;

  // A (ET rows) -> registers: lane ln holds row g0+wr*16+ln, k = qd*8 + tt*32 .. +8
  bf16x8 areg[16];
  {
    const u16* ar = ET + (size_t)(g0 + wr * 16 + ln) * R_ + qd * 8;
    #pragma unroll
    for (int tt = 0; tt < 16; tt++) areg[tt] = *(const bf16x8*)(ar + tt * 32);
  }
  float esqp[4] = {0.f, 0.f, 0.f, 0.f};

  // wave wv stages 8 d-rows of the ct-tile; lane l fetches global chunk l^(d&7) into slot l
#define STAGE_E(TB, ct) do {                                           \
    _Pragma("unroll")                                                  \
    for (int i_ = 0; i_ < 8; i_++) {                                   \
      int dl_ = wv * 8 + i_;                                           \
      int gc_ = lane ^ (dl_ & 7);                                      \
      gload16(Bp + (size_t)((ct) * 64 + dl_) * R_ + gc_ * 8,           \
              TB + dl_ * 512);                                         \
    }                                                                  \
  } while (0)

#define COMPUTE_E(TB, ct) do {                                                        \
    f32x4 cacc0 = (f32x4){0.f,0.f,0.f,0.f};                                           \
    f32x4 cacc1 = (f32x4){0.f,0.f,0.f,0.f};                                           \
    _Pragma("unroll")                                                                 \
    for (int kt_ = 0; kt_ < 16; kt_++) {                                              \
      int slot_ = (kt_ * 4 + qd) ^ (ln & 7);                                          \
      bf16x8 bfr0 = *(bf16x8*)&TB[(wc * 32 + ln) * 512 + slot_ * 8];                  \
      bf16x8 bfr1 = *(bf16x8*)&TB[(wc * 32 + 16 + ln) * 512 + slot_ * 8];             \
      cacc0 = __builtin_amdgcn_mfma_f32_16x16x32_bf16(areg[kt_], bfr0, cacc0, 0,0,0); \
      cacc1 = __builtin_amdgcn_mfma_f32_16x16x32_bf16(areg[kt_], bfr1, cacc1, 0,0,0); \
    }                                                                                 \
    _Pragma("unroll")                                                                 \
    for (int r_ = 0; r_ < 4; r_++) {                                                  \
      int c_ = g0 + wr * 16 + qd * 4 + r_;                                            \
      int d0_ = (ct) * 64 + wc * 32 + ln;                                             \
      float v0_ = cacc0[r_], v1_ = cacc1[r_];                                         \
      embT[((size_t)b * C_ + c_) * D_ + d0_]      = f2bf(v0_);                        \
      embT[((size_t)b * C_ + c_) * D_ + d0_ + 16] = f2bf(v1_);                        \
      esqp[r_] += v0_ * v0_ + v1_ * v1_;                                              \
    }                                                                                 \
  } while (0)

  STAGE_E(tE0, 0);
  __syncthreads();
  for (int ct = 0; ct < 4; ct += 2) {
    STAGE_E(tE1, ct + 1);                      // async prefetch into other symbol
    COMPUTE_E(tE0, ct);                        // 32 MFMA + 32 ds_read hides it
    __syncthreads();
    if (ct + 2 < 4) STAGE_E(tE0, ct + 2);
    COMPUTE_E(tE1, ct + 1);
    __syncthreads();
  }
#undef STAGE_E
#undef COMPUTE_E

  // esq: reduce over d (16 lanes of each qd group cover disjoint d; rows fixed per (qd,reg))
  #pragma unroll
  for (int r = 0; r < 4; r++) {
    #pragma unroll
    for (int off = 1; off < 16; off <<= 1) esqp[r] += __shfl_xor(esqp[r], off);
  }
  if (ln == 0) {
    #pragma unroll
    for (int r = 0; r < 4; r++) sesq[wc][wr * 16 + qd * 4 + r] = esqp[r];
  }
  __syncthreads();
  if (tid < 64) esq[b * C_ + g0 + tid] = sesq[0][tid] + sesq[1][tid];
}

// ======== K4: dist — R3-VERBATIM (proven 72.5-75.7us): persistent 128-row blocks, areg[2][8],
//          static-symbol dbuf, fused argmin+hist+SSE+gather. ========
__global__ __launch_bounds__(512) void k_dist(const u16* __restrict__ posb,
                                              const u16* __restrict__ embT,
                                              const float* __restrict__ esq,
                                              const float* __restrict__ qsq,
                                              int* __restrict__ hist,
                                              float* __restrict__ acc,
                                              float* __restrict__ out) {
  int b = blockIdx.x, st = blockIdx.y;
  int m0 = st * 128;
  const u16* A  = posb + (size_t)b * S_ * D_;   // S x D
  const u16* Bt = embT + (size_t)b * C_ * D_;   // C x D
  __shared__ u16 tB0[128 * 256];                // 64 KB
  __shared__ u16 tB1[128 * 256];                // 64 KB
  __shared__ float sh_esq[2048];                // 8 KB
  __shared__ float pbv[2][128];
  __shared__ int   pbi[2][128];
  __shared__ int   fidx[128];
  int tid = threadIdx.x;
  int wv = tid >> 6, lane = tid & 63, ln = lane & 15, qd = lane >> 4;
  int wr = wv >> 1, wc = wv & 1;

  *(float4*)&sh_esq[tid * 4] = *(const float4*)&esq[b * C_ + tid * 4];

  bf16x8 areg[2][8];
  #pragma unroll
  for (int mi = 0; mi < 2; mi++) {
    const u16* ar = A + (size_t)(m0 + wr * 32 + mi * 16 + ln) * D_ + qd * 8;
    #pragma unroll
    for (int t = 0; t < 8; t++) areg[mi][t] = *(const bf16x8*)(ar + t * 32);
  }

  float rbv[2][4]; int rbc[2][4];
  #pragma unroll
  for (int mi = 0; mi < 2; mi++)
    #pragma unroll
    for (int r = 0; r < 4; r++) { rbv[mi][r] = 3.4e38f; rbc[mi][r] = 0; }

#define STAGE_D(TB, ct) do {                                                        \
    _Pragma("unroll")                                                               \
    for (int i_ = 0; i_ < 8; i_++) {                                                \
      int c0_ = wv * 16 + i_ * 2;                                                   \
      int cl_ = c0_ + (lane >> 5);                                                  \
      int gc_ = (lane & 31) ^ (cl_ & 7);                                            \
      gload16(Bt + (size_t)((ct) * 128 + cl_) * D_ + gc_ * 8, TB + c0_ * 256);      \
    }                                                                               \
  } while (0)

#define COMPUTE_D(TB, ct) do {                                                      \
    f32x4 cacc[2][4];                                                               \
    _Pragma("unroll")                                                               \
    for (int mi_ = 0; mi_ < 2; mi_++)                                               \
      _Pragma("unroll")                                                             \
      for (int cf_ = 0; cf_ < 4; cf_++) cacc[mi_][cf_] = (f32x4){0.f,0.f,0.f,0.f};  \
    _Pragma("unroll")                                                               \
    for (int kt_ = 0; kt_ < 8; kt_++) {                                             \
      bf16x8 bfr[4];                                                                \
      _Pragma("unroll")                                                             \
      for (int cf_ = 0; cf_ < 4; cf_++) {                                           \
        int col_ = wc * 64 + cf_ * 16 + ln;                                         \
        int slot_ = (kt_ * 4 + qd) ^ (ln & 7);                                      \
        bfr[cf_] = *(bf16x8*)&TB[col_ * 256 + slot_ * 8];                           \
      }                                                                             \
      _Pragma("unroll")                                                             \
      for (int mi_ = 0; mi_ < 2; mi_++)                                             \
        _Pragma("unroll")                                                           \
        for (int cf_ = 0; cf_ < 4; cf_++)                                           \
          cacc[mi_][cf_] = __builtin_amdgcn_mfma_f32_16x16x32_bf16(                 \
              areg[mi_][kt_], bfr[cf_], cacc[mi_][cf_], 0, 0, 0);                   \
    }                                                                               \
    _Pragma("unroll")                                                               \
    for (int mi_ = 0; mi_ < 2; mi_++)                                               \
      _Pragma("unroll")                                                             \
      for (int cf_ = 0; cf_ < 4; cf_++) {                                           \
        int c_ = (ct) * 128 + wc * 64 + cf_ * 16 + ln;                              \
        float e_ = sh_esq[c_];                                                      \
        _Pragma("unroll")                                                           \
        for (int r_ = 0; r_ < 4; r_++) {                                            \
          float s_ = e_ - 2.0f * cacc[mi_][cf_][r_];                                \
          if (s_ < rbv[mi_][r_] || (s_ == rbv[mi_][r_] && c_ < rbc[mi_][r_])) {     \
            rbv[mi_][r_] = s_; rbc[mi_][r_] = c_;                                   \
          }                                                                         \
        }                                                                           \
      }                                                                             \
  } while (0)

  STAGE_D(tB0, 0);
  __syncthreads();
  for (int ct = 0; ct < 16; ct += 2) {
    STAGE_D(tB1, ct + 1);
    COMPUTE_D(tB0, ct);
    __syncthreads();
    if (ct + 2 < 16) STAGE_D(tB0, ct + 2);
    COMPUTE_D(tB1, ct + 1);
    __syncthreads();
  }
#undef STAGE_D
#undef COMPUTE_D

  #pragma unroll
  for (int mi = 0; mi < 2; mi++)
    #pragma unroll
    for (int r = 0; r < 4; r++) {
      float bv = rbv[mi][r]; int bc = rbc[mi][r];
      #pragma unroll
      for (int off = 1; off < 16; off <<= 1) {
        float ov = __shfl_xor(bv, off);
        int   oc = __shfl_xor(bc, off);
        if (ov < bv || (ov == bv && oc < bc)) { bv = ov; bc = oc; }
      }
      if (ln == 0) {
        int rl = wr * 32 + mi * 16 + qd * 4 + r;
        pbv[wc][rl] = bv;
        pbi[wc][rl] = bc;
      }
    }
  __syncthreads();
  if (tid < 128) {
    float v0 = pbv[0][tid]; int i0 = pbi[0][tid];
    float v1 = pbv[1][tid]; int i1 = pbi[1][tid];
    if (v1 < v0 || (v1 == v0 && i1 < i0)) { v0 = v1; i0 = i1; }
    fidx[tid] = i0;
    atomicAdd(&hist[b * C_ + i0], 1);
    float sse = v0 + qsq[b * S_ + m0 + tid];
    #pragma unroll
    for (int off = 1; off < 64; off <<= 1) sse += __shfl_xor(sse, off);
    if (lane == 0) atomicAdd(&acc[0], sse);
  }
  __syncthreads();
  size_t xb = (size_t)b * SP1_ * D_;
  #pragma unroll
  for (int j = 0; j < 16; j++) {
    int r = wv * 16 + j;
    int ix = fidx[r];
    int s = m0 + r;
    ushort4 q4 = *(const ushort4*)(Bt + (size_t)ix * D_ + lane * 4);
    float4 q;
    q.x = bf2f(q4.x); q.y = bf2f(q4.y); q.z = bf2f(q4.z); q.w = bf2f(q4.w);
    *(float4*)(out + xb + (size_t)(s + 1) * D_ + lane * 4) = q;
  }
}

// ================= K5: perplexity + final scalars (R0-proven) =================
__global__ void k_perp(const int* __restrict__ hist, float* __restrict__ acc,
                       float* __restrict__ out) {
  int b = blockIdx.x, t = threadIdx.x;
  float ps = 0.f;
  for (int c = t; c < C_; c += 256) {
    float p = (float)hist[b * C_ + c] * (1.0f / (float)S_);
    ps += p * logf(p + 1e-10f);
  }
  __shared__ float red[256];
  red[t] = ps;
  __syncthreads();
  for (int st = 128; st; st >>= 1) { if (t < st) red[t] += red[t + st]; __syncthreads(); }
  if (t == 0) {
    atomicAdd(&acc[1], expf(-red[0]) * (1.0f / (float)B_));
    __threadfence();
    int done = atomicAdd((int*)acc + 2, 1);
    if (done == B_ - 1) {
      float P = atomicAdd(&acc[1], 0.0f);
      float SSE = atomicAdd(&acc[0], 0.0f);
      float L = SSE * (1.0f / 8388608.0f);
      size_t base = (size_t)B_ * SP1_ * D_;
      out[base + 0] = P;
      out[base + 1] = L;
      out[base + 2] = L;
      out[base + 3] = L + 0.25f * L;
    }
  }
}

// ---------------- workspace layout (bytes); esq/hist/acc contiguous (zeroed by K1) ----------------
#define OFF_W0    0u
#define OFF_ESQ   16384u
#define OFF_HIST  (OFF_ESQ + 65536u)
#define OFF_ACC   (OFF_HIST + 65536u)
#define OFF_PROJ  (OFF_ACC + 256u)
#define OFF_ET    (OFF_PROJ + 2097152u)
#define OFF_EMBT  (OFF_ET + 2097152u)
#define OFF_POSB  (OFF_EMBT + 8388608u)
#define OFF_QSQ   (OFF_POSB + 16777216u)

extern "C" void kernel_launch(void* const* d_in, const int* in_sizes, int n_in,
                              void* d_out, int out_size, void* d_ws, size_t ws_size,
                              hipStream_t stream) {
  (void)in_sizes; (void)n_in; (void)out_size; (void)ws_size;
  const float* x    = (const float*)d_in[0];
  const float* E    = (const float*)d_in[1];
  const float* clsw = (const float*)d_in[2];
  const float* clsb = (const float*)d_in[3];
  float* out = (float*)d_out;

  char* ws = (char*)d_ws;
  float* w0   = (float*)(ws + OFF_W0);
  float* esq  = (float*)(ws + OFF_ESQ);
  int*   hist = (int*)  (ws + OFF_HIST);
  float* acc  = (float*)(ws + OFF_ACC);
  u16*   proj = (u16*)  (ws + OFF_PROJ);
  u16*   ET   = (u16*)  (ws + OFF_ET);
  u16*   embT = (u16*)  (ws + OFF_EMBT);
  u16*   posb = (u16*)  (ws + OFF_POSB);
  float* qsq  = (float*)(ws + OFF_QSQ);

  k_prep<<<K1GRID, 256, 0, stream>>>(x, clsw, E, posb, qsq, w0, ET, esq, out);
  k_softmax<<<B_ * D_, 256, 0, stream>>>(x, w0, clsb, proj);
  k_emb2<<<dim3(8, 32), 512, 0, stream>>>(proj, ET, embT, esq);
  k_dist<<<dim3(8, 32), 512, 0, stream>>>(posb, embT, esq, qsq, hist, acc, out);
  k_perp<<<B_, 256, 0, stream>>>(hist, acc, out);
}

// Round 10
// 183.891 us; speedup vs baseline: 2.9412x; 1.0384x over previous
//
#include <hip/hip_runtime.h>
#include <hip/hip_bf16.h>
#include <stdint.h>

#define B_   8
#define S_   4096
#define SP1_ 4097
#define D_   256
#define R_   512
#define C_   2048

typedef __attribute__((ext_vector_type(8))) short bf16x8;
typedef __attribute__((ext_vector_type(4))) float f32x4;
typedef __attribute__((ext_vector_type(16))) float f32x16;
typedef unsigned short u16;

__device__ __forceinline__ u16 f2bf(float f) {
  __hip_bfloat16 h = __float2bfloat16(f);
  return *(u16*)&h;
}
__device__ __forceinline__ float bf2f(u16 u) {
  __hip_bfloat16 h = *(__hip_bfloat16*)&u;
  return __bfloat162float(h);
}
__device__ __forceinline__ f32x16 zero16() {
  f32x16 z;
  #pragma unroll
  for (int i = 0; i < 16; i++) z[i] = 0.f;
  return z;
}

// async global->LDS, 16B per lane; LDS dst = wave-uniform base + lane*16
__device__ __forceinline__ void gload16(const u16* g, u16* l) {
  __builtin_amdgcn_global_load_lds(
      (const __attribute__((address_space(1))) uint32_t*)g,
      (__attribute__((address_space(3))) uint32_t*)l, 16, 0, 0);
}

// ================= K1: prep (cast+qsq | w0 | transpose_E | zero | cls copy) — R3-verbatim =================
#define NCAST 8192
#define W0B   (NCAST)            // 64 blocks
#define TEB   (W0B + 64)         // 1024 blocks
#define ZB    (TEB + 1024)       // 33 blocks
#define CLSB  (ZB + 33)          // 8 blocks
#define K1GRID (CLSB + 8)

__global__ void k_prep(const float* __restrict__ x, const float* __restrict__ clsw,
                       const float* __restrict__ E, u16* __restrict__ posb,
                       float* __restrict__ qsq, float* __restrict__ w0,
                       u16* __restrict__ ET, float* __restrict__ zbase,
                       float* __restrict__ out) {
  __shared__ float sm[33 * 32];
  int blk = blockIdx.x, t = threadIdx.x;
  if (blk < NCAST) {
    int wv = t >> 6, lane = t & 63;
    int row = blk * 4 + wv;
    int b = row >> 12, s = row & 4095;
    const float4 v = *(const float4*)(x + (size_t)b * SP1_ * D_ + (size_t)(s + 1) * D_ + lane * 4);
    ushort4 u;
    u.x = f2bf(v.x); u.y = f2bf(v.y); u.z = f2bf(v.z); u.w = f2bf(v.w);
    *(ushort4*)(posb + (size_t)row * D_ + lane * 4) = u;
    float ss = v.x * v.x + v.y * v.y + v.z * v.z + v.w * v.w;
    #pragma unroll
    for (int off = 1; off < 64; off <<= 1) ss += __shfl_xor(ss, off);
    if (lane == 0) qsq[row] = ss;
  } else if (blk < TEB) {
    int id = blk - W0B;                       // 0..63 = b*8 + rc
    int b = id >> 3, rc = id & 7;
    int r = rc * 64 + (t & 63);
    int dg = t >> 6;
    const float* cls = x + (size_t)b * SP1_ * D_;
    float a = 0.f;
    for (int d = dg * 64; d < dg * 64 + 64; d++) a += cls[d] * clsw[d * R_ + r];
    sm[t] = a;
    __syncthreads();
    if (t < 64) w0[b * R_ + r] = sm[t] + sm[t + 64] + sm[t + 128] + sm[t + 192];
  } else if (blk < ZB) {
    int id = blk - TEB;                       // 0..1023
    int c0 = (id & 63) * 32, r0 = (id >> 6) * 32;
    int tx = t & 31, ty = t >> 5;             // 32 x 8
    float (*tile)[33] = (float(*)[33])sm;
    #pragma unroll
    for (int i = 0; i < 4; i++)
      tile[ty + i * 8][tx] = E[(size_t)(r0 + ty + i * 8) * C_ + c0 + tx];
    __syncthreads();
    #pragma unroll
    for (int i = 0; i < 4; i++)
      ET[(size_t)(c0 + ty + i * 8) * R_ + r0 + tx] = f2bf(tile[tx][ty + i * 8]);
  } else if (blk < CLSB) {
    int id = blk - ZB;
    int o1 = id * 1024 + t;       if (o1 < 32832) ((uint32_t*)zbase)[o1] = 0u;
    int o2 = id * 1024 + 256 + t; if (o2 < 32832) ((uint32_t*)zbase)[o2] = 0u;
    int o3 = id * 1024 + 512 + t; if (o3 < 32832) ((uint32_t*)zbase)[o3] = 0u;
    int o4 = id * 1024 + 768 + t; if (o4 < 32832) ((uint32_t*)zbase)[o4] = 0u;
  } else {
    int b = blk - CLSB;
    size_t xb = (size_t)b * SP1_ * D_;
    if (t < 64) *(float4*)(out + xb + t * 4) = *(const float4*)(x + xb + t * 4);
  }
}

// ================= K2: softmax -> proj bf16 (R0-proven) =================
__global__ void k_softmax(const float* __restrict__ x, const float* __restrict__ w0,
                          const float* __restrict__ clsb, u16* __restrict__ proj) {
  int bd = blockIdx.x;
  int b = bd >> 8, d = bd & 255;
  float c = x[(size_t)b * SP1_ * D_ + d];
  int t = threadIdx.x;
  float l0 = c * w0[b * R_ + t] + clsb[t];
  float l1 = c * w0[b * R_ + t + 256] + clsb[t + 256];
  __shared__ float red[256];
  red[t] = fmaxf(l0, l1);
  __syncthreads();
  for (int st = 128; st; st >>= 1) { if (t < st) red[t] = fmaxf(red[t], red[t + st]); __syncthreads(); }
  float m = red[0];
  __syncthreads();
  float e0 = expf(l0 - m), e1 = expf(l1 - m);
  red[t] = e0 + e1;
  __syncthreads();
  for (int st = 128; st; st >>= 1) { if (t < st) red[t] += red[t + st]; __syncthreads(); }
  float inv = 1.0f / red[0];
  size_t base = ((size_t)b * D_ + d) * R_;
  proj[base + t]       = f2bf(e0 * inv);
  proj[base + t + 256] = f2bf(e1 * inv);
}

// ======== K3: emb2 — R9-verbatim persistent GEMM: embT[c][d] = sum_k ET[c][k]*proj[d][k] ========
__global__ __launch_bounds__(512) void k_emb2(const u16* __restrict__ proj,
                                              const u16* __restrict__ ET,
                                              u16* __restrict__ embT,
                                              float* __restrict__ esq) {
  int b = blockIdx.x, cg = blockIdx.y;
  int g0 = cg * 64;
  const u16* Bp = proj + (size_t)b * D_ * R_;  // d-rows x R (B operand)
  __shared__ u16 tE0[64 * 512];                // 64 KB
  __shared__ u16 tE1[64 * 512];                // 64 KB
  __shared__ float sesq[2][64];
  int tid = threadIdx.x;
  int wv = tid >> 6, lane = tid & 63, ln = lane & 15, qd = lane >> 4;
  int wr = wv >> 1, wc = wv & 1;

  bf16x8 areg[16];
  {
    const u16* ar = ET + (size_t)(g0 + wr * 16 + ln) * R_ + qd * 8;
    #pragma unroll
    for (int tt = 0; tt < 16; tt++) areg[tt] = *(const bf16x8*)(ar + tt * 32);
  }
  float esqp[4] = {0.f, 0.f, 0.f, 0.f};

#define STAGE_E(TB, ct) do {                                           \
    _Pragma("unroll")                                                  \
    for (int i_ = 0; i_ < 8; i_++) {                                   \
      int dl_ = wv * 8 + i_;                                           \
      int gc_ = lane ^ (dl_ & 7);                                      \
      gload16(Bp + (size_t)((ct) * 64 + dl_) * R_ + gc_ * 8,           \
              TB + dl_ * 512);                                         \
    }                                                                  \
  } while (0)

#define COMPUTE_E(TB, ct) do {                                                        \
    f32x4 cacc0 = (f32x4){0.f,0.f,0.f,0.f};                                           \
    f32x4 cacc1 = (f32x4){0.f,0.f,0.f,0.f};                                           \
    _Pragma("unroll")                                                                 \
    for (int kt_ = 0; kt_ < 16; kt_++) {                                              \
      int slot_ = (kt_ * 4 + qd) ^ (ln & 7);                                          \
      bf16x8 bfr0 = *(bf16x8*)&TB[(wc * 32 + ln) * 512 + slot_ * 8];                  \
      bf16x8 bfr1 = *(bf16x8*)&TB[(wc * 32 + 16 + ln) * 512 + slot_ * 8];             \
      cacc0 = __builtin_amdgcn_mfma_f32_16x16x32_bf16(areg[kt_], bfr0, cacc0, 0,0,0); \
      cacc1 = __builtin_amdgcn_mfma_f32_16x16x32_bf16(areg[kt_], bfr1, cacc1, 0,0,0); \
    }                                                                                 \
    _Pragma("unroll")                                                                 \
    for (int r_ = 0; r_ < 4; r_++) {                                                  \
      int c_ = g0 + wr * 16 + qd * 4 + r_;                                            \
      int d0_ = (ct) * 64 + wc * 32 + ln;                                             \
      float v0_ = cacc0[r_], v1_ = cacc1[r_];                                         \
      embT[((size_t)b * C_ + c_) * D_ + d0_]      = f2bf(v0_);                        \
      embT[((size_t)b * C_ + c_) * D_ + d0_ + 16] = f2bf(v1_);                        \
      esqp[r_] += v0_ * v0_ + v1_ * v1_;                                              \
    }                                                                                 \
  } while (0)

  STAGE_E(tE0, 0);
  __syncthreads();
  for (int ct = 0; ct < 4; ct += 2) {
    STAGE_E(tE1, ct + 1);
    COMPUTE_E(tE0, ct);
    __syncthreads();
    if (ct + 2 < 4) STAGE_E(tE0, ct + 2);
    COMPUTE_E(tE1, ct + 1);
    __syncthreads();
  }
#undef STAGE_E
#undef COMPUTE_E

  #pragma unroll
  for (int r = 0; r < 4; r++) {
    #pragma unroll
    for (int off = 1; off < 16; off <<= 1) esqp[r] += __shfl_xor(esqp[r], off);
  }
  if (ln == 0) {
    #pragma unroll
    for (int r = 0; r < 4; r++) sesq[wc][wr * 16 + qd * 4 + r] = esqp[r];
  }
  __syncthreads();
  if (tid < 64) esq[b * C_ + g0 + tid] = sesq[0][tid] + sesq[1][tid];
}

// ======== K4: dist — 32x32x16 MFMA variant (halved LDS read amplification) ========
// Grid (8 b, 32 st) = 256 blocks = 1/CU (LDS-limited). 512 thr = 8 waves.
// Wave (wr,wc)=(wv>>1, wv&1): rows wr*32 (one 32-row MFMA strip), cols wc*64 (2 of 32).
// A (32 rows x K=256) in regs: areg[16], layout row=lane&31, k=kt*16+(lane>>5)*8+j (64 VGPR).
// B LDS layout/staging/swizzle IDENTICAL to the proven R3 kernel.
// C/D layout [HW-verified m74/m101]: col=lane&31, row=(reg&3)+8*(reg>>2)+4*(lane>>5).
__global__ __launch_bounds__(512) void k_dist(const u16* __restrict__ posb,
                                              const u16* __restrict__ embT,
                                              const float* __restrict__ esq,
                                              const float* __restrict__ qsq,
                                              int* __restrict__ hist,
                                              float* __restrict__ acc,
                                              float* __restrict__ out) {
  int b = blockIdx.x, st = blockIdx.y;
  int m0 = st * 128;
  const u16* A  = posb + (size_t)b * S_ * D_;   // S x D
  const u16* Bt = embT + (size_t)b * C_ * D_;   // C x D
  __shared__ u16 tB0[128 * 256];                // 64 KB
  __shared__ u16 tB1[128 * 256];                // 64 KB
  __shared__ float sh_esq[2048];                // 8 KB
  __shared__ float pbv[2][128];
  __shared__ int   pbi[2][128];
  __shared__ int   fidx[128];
  int tid = threadIdx.x;
  int wv = tid >> 6, lane = tid & 63;
  int l32 = lane & 31, hi = lane >> 5;
  int wr = wv >> 1, wc = wv & 1;

  *(float4*)&sh_esq[tid * 4] = *(const float4*)&esq[b * C_ + tid * 4];

  // A fragments: lane holds row m0+wr*32+l32; areg[kt] = k in [kt*16 + hi*8, +8)
  bf16x8 areg[16];
  {
    const u16* ar = A + (size_t)(m0 + wr * 32 + l32) * D_ + hi * 8;
    #pragma unroll
    for (int kt = 0; kt < 16; kt++) areg[kt] = *(const bf16x8*)(ar + kt * 16);
  }

  float rbv[16]; int rbc[16];
  #pragma unroll
  for (int r = 0; r < 16; r++) { rbv[r] = 3.4e38f; rbc[r] = 0; }

  // staging identical to R3 (layout: slot s of col c holds global 16B-chunk s^(c&7))
#define STAGE_D(TB, ct) do {                                                        \
    _Pragma("unroll")                                                               \
    for (int i_ = 0; i_ < 8; i_++) {                                                \
      int c0_ = wv * 16 + i_ * 2;                                                   \
      int cl_ = c0_ + (lane >> 5);                                                  \
      int gc_ = (lane & 31) ^ (cl_ & 7);                                            \
      gload16(Bt + (size_t)((ct) * 128 + cl_) * D_ + gc_ * 8, TB + c0_ * 256);      \
    }                                                                               \
  } while (0)

  // per ct-tile: 16 kt x 2 col-frags = 32 MFMA(32x32x16), 32 ds_read_b128 per wave
#define COMPUTE_D(TB, ct) do {                                                      \
    f32x16 cacc0 = zero16();                                                        \
    f32x16 cacc1 = zero16();                                                        \
    _Pragma("unroll")                                                               \
    for (int kt_ = 0; kt_ < 16; kt_++) {                                            \
      int sl_ = (kt_ * 2 + hi) ^ (l32 & 7);   /* chunk kt*2+hi of col; col&7=l32&7 */\
      bf16x8 b0_ = *(bf16x8*)&TB[(wc * 64 + l32) * 256 + sl_ * 8];                  \
      bf16x8 b1_ = *(bf16x8*)&TB[(wc * 64 + 32 + l32) * 256 + sl_ * 8];             \
      cacc0 = __builtin_amdgcn_mfma_f32_32x32x16_bf16(areg[kt_], b0_, cacc0, 0,0,0);\
      cacc1 = __builtin_amdgcn_mfma_f32_32x32x16_bf16(areg[kt_], b1_, cacc1, 0,0,0);\
    }                                                                               \
    int c0_ = (ct) * 128 + wc * 64 + l32;                                           \
    int c1_ = c0_ + 32;                                                             \
    float e0_ = sh_esq[c0_];                                                        \
    float e1_ = sh_esq[c1_];                                                        \
    _Pragma("unroll")                                                               \
    for (int r_ = 0; r_ < 16; r_++) {                                               \
      float s0_ = e0_ - 2.0f * cacc0[r_];                                           \
      if (s0_ < rbv[r_] || (s0_ == rbv[r_] && c0_ < rbc[r_])) {                     \
        rbv[r_] = s0_; rbc[r_] = c0_;                                               \
      }                                                                             \
      float s1_ = e1_ - 2.0f * cacc1[r_];                                           \
      if (s1_ < rbv[r_] || (s1_ == rbv[r_] && c1_ < rbc[r_])) {                     \
        rbv[r_] = s1_; rbc[r_] = c1_;                                               \
      }                                                                             \
    }                                                                               \
  } while (0)

  STAGE_D(tB0, 0);
  __syncthreads();
  for (int ct = 0; ct < 16; ct += 2) {
    STAGE_D(tB1, ct + 1);                       // async prefetch (distinct symbol)
    COMPUTE_D(tB0, ct);
    __syncthreads();
    if (ct + 2 < 16) STAGE_D(tB0, ct + 2);
    COMPUTE_D(tB1, ct + 1);
    __syncthreads();
  }
#undef STAGE_D
#undef COMPUTE_D

  // reduce across the 32 cols of each half-wave (rows disjoint by hi; offsets stay in-half)
  #pragma unroll
  for (int r = 0; r < 16; r++) {
    float bv = rbv[r]; int bc = rbc[r];
    #pragma unroll
    for (int off = 1; off < 32; off <<= 1) {
      float ov = __shfl_xor(bv, off);
      int   oc = __shfl_xor(bc, off);
      if (ov < bv || (ov == bv && oc < bc)) { bv = ov; bc = oc; }
    }
    if (l32 == 0) {
      int rl = wr * 32 + (r & 3) + 8 * (r >> 2) + 4 * hi;   // 0..127
      pbv[wc][rl] = bv;
      pbi[wc][rl] = bc;
    }
  }
  __syncthreads();
  // combine col-halves, hist, SSE (unchanged)
  if (tid < 128) {
    float v0 = pbv[0][tid]; int i0 = pbi[0][tid];
    float v1 = pbv[1][tid]; int i1 = pbi[1][tid];
    if (v1 < v0 || (v1 == v0 && i1 < i0)) { v0 = v1; i0 = i1; }
    fidx[tid] = i0;
    atomicAdd(&hist[b * C_ + i0], 1);
    float sse = v0 + qsq[b * S_ + m0 + tid];
    #pragma unroll
    for (int off = 1; off < 64; off <<= 1) sse += __shfl_xor(sse, off);
    if (lane == 0) atomicAdd(&acc[0], sse);
  }
  __syncthreads();
  // gather + write out (wave wv owns rows wv*16..+15) — unchanged
  size_t xb = (size_t)b * SP1_ * D_;
  #pragma unroll
  for (int j = 0; j < 16; j++) {
    int r = wv * 16 + j;
    int ix = fidx[r];
    int s = m0 + r;
    ushort4 q4 = *(const ushort4*)(Bt + (size_t)ix * D_ + lane * 4);
    float4 q;
    q.x = bf2f(q4.x); q.y = bf2f(q4.y); q.z = bf2f(q4.z); q.w = bf2f(q4.w);
    *(float4*)(out + xb + (size_t)(s + 1) * D_ + lane * 4) = q;
  }
}

// ================= K5: perplexity + final scalars (R0-proven) =================
__global__ void k_perp(const int* __restrict__ hist, float* __restrict__ acc,
                       float* __restrict__ out) {
  int b = blockIdx.x, t = threadIdx.x;
  float ps = 0.f;
  for (int c = t; c < C_; c += 256) {
    float p = (float)hist[b * C_ + c] * (1.0f / (float)S_);
    ps += p * logf(p + 1e-10f);
  }
  __shared__ float red[256];
  red[t] = ps;
  __syncthreads();
  for (int st = 128; st; st >>= 1) { if (t < st) red[t] += red[t + st]; __syncthreads(); }
  if (t == 0) {
    atomicAdd(&acc[1], expf(-red[0]) * (1.0f / (float)B_));
    __threadfence();
    int done = atomicAdd((int*)acc + 2, 1);
    if (done == B_ - 1) {
      float P = atomicAdd(&acc[1], 0.0f);
      float SSE = atomicAdd(&acc[0], 0.0f);
      float L = SSE * (1.0f / 8388608.0f);
      size_t base = (size_t)B_ * SP1_ * D_;
      out[base + 0] = P;
      out[base + 1] = L;
      out[base + 2] = L;
      out[base + 3] = L + 0.25f * L;
    }
  }
}

// ---------------- workspace layout (bytes); esq/hist/acc contiguous (zeroed by K1) ----------------
#define OFF_W0    0u
#define OFF_ESQ   16384u
#define OFF_HIST  (OFF_ESQ + 65536u)
#define OFF_ACC   (OFF_HIST + 65536u)
#define OFF_PROJ  (OFF_ACC + 256u)
#define OFF_ET    (OFF_PROJ + 2097152u)
#define OFF_EMBT  (OFF_ET + 2097152u)
#define OFF_POSB  (OFF_EMBT + 8388608u)
#define OFF_QSQ   (OFF_POSB + 16777216u)

extern "C" void kernel_launch(void* const* d_in, const int* in_sizes, int n_in,
                              void* d_out, int out_size, void* d_ws, size_t ws_size,
                              hipStream_t stream) {
  (void)in_sizes; (void)n_in; (void)out_size; (void)ws_size;
  const float* x    = (const float*)d_in[0];
  const float* E    = (const float*)d_in[1];
  const float* clsw = (const float*)d_in[2];
  const float* clsb = (const float*)d_in[3];
  float* out = (float*)d_out;

  char* ws = (char*)d_ws;
  float* w0   = (float*)(ws + OFF_W0);
  float* esq  = (float*)(ws + OFF_ESQ);
  int*   hist = (int*)  (ws + OFF_HIST);
  float* acc  = (float*)(ws + OFF_ACC);
  u16*   proj = (u16*)  (ws + OFF_PROJ);
  u16*   ET   = (u16*)  (ws + OFF_ET);
  u16*   embT = (u16*)  (ws + OFF_EMBT);
  u16*   posb = (u16*)  (ws + OFF_POSB);
  float* qsq  = (float*)(ws + OFF_QSQ);

  k_prep<<<K1GRID, 256, 0, stream>>>(x, clsw, E, posb, qsq, w0, ET, esq, out);
  k_softmax<<<B_ * D_, 256, 0, stream>>>(x, w0, clsb, proj);
  k_emb2<<<dim3(8, 32), 512, 0, stream>>>(proj, ET, embT, esq);
  k_dist<<<dim3(8, 32), 512, 0, stream>>>(posb, embT, esq, qsq, hist, acc, out);
  k_perp<<<B_, 256, 0, stream>>>(hist, acc, out);
}